// Round 1
// baseline (2441.715 us; speedup 1.0000x reference)
//
#include <hip/hip_runtime.h>
#include <math.h>

// ---- problem constants ----
#define NB 4
#define NVAL 3
#define NC 128
#define NHW 128
#define NHEAD 4
#define NPOINT 4
#define NLVL 3
#define WSZ 8
#define HD 32
#define NWIN 256      // 16x16 windows
#define BWTOT 1024    // NB * NWIN
#define NPIX 64       // WSZ*WSZ

// ---- workspace layout (float offsets) ----
#define WS_SO1BA 0                        // 4*64
#define WS_AW1BA 256                      // 4*64
#define WS_VB    512                      // 3*128
#define WS_HS    896                      // 4*3*4
#define WS_ABSDT 944                      // 4*3
#define WS_COORD 1024                     // 1024*64*4*12*2 = 6291456
#define WS_ATTN  (1024 + 6291456)         // 1024*64*4*12 = 3145728
#define WS_VFLAT (1024 + 6291456 + 3145728) // 3*1024*4*64*32 = 25165824

// ---- output layout (float offsets) ----
#define OUT_FUSED 0
#define OUT_CONF  8388608                 // 4*128*128*128
#define OUT_ENT   (8388608 + 65536)

__device__ __forceinline__ int ufl(int x) { return __builtin_amdgcn_readfirstlane(x); }

// ============================================================
// K0: prep — film-folded biases, vproj level bias, hscale, |dt|
// ============================================================
__global__ __launch_bounds__(256) void prep_kernel(
    const float* __restrict__ tgt_enc, const float* __restrict__ filmo_w, const float* __restrict__ filmo_b,
    const float* __restrict__ filma_w, const float* __restrict__ filma_b,
    const float* __restrict__ so1_w, const float* __restrict__ so1_b,
    const float* __restrict__ aw1_w, const float* __restrict__ aw1_b,
    const float* __restrict__ vproj_w, const float* __restrict__ vproj_b,
    const float* __restrict__ level_embed,
    const float* __restrict__ rel_scalar, const float* __restrict__ dts_w, const float* __restrict__ dts_b,
    float* __restrict__ ws)
{
    __shared__ float film[1024];  // [which][b][c] = which*512 + b*128 + c
    int tid = threadIdx.x;
    for (int t = tid; t < 1024; t += 256) {
        int which = t >> 9; int b = (t >> 7) & 3; int c = t & 127;
        const float* fw = which ? filma_w : filmo_w;
        const float* fb = which ? filma_b : filmo_b;
        float acc = fb[c];
        for (int k = 0; k < 64; ++k) acc += tgt_enc[b * 64 + k] * fw[c * 64 + k];
        film[t] = acc;
    }
    __syncthreads();
    for (int t = tid; t < 512; t += 256) {
        int which = t >> 8; int fb = (t >> 6) & 3; int o = t & 63;
        const float* w  = which ? aw1_w : so1_w;
        const float* bb = which ? aw1_b : so1_b;
        const float* fm = &film[which * 512 + fb * 128];
        float acc = bb[o];
        for (int c = 0; c < 128; ++c) acc += w[o * 128 + c] * fm[c];
        ws[(which ? WS_AW1BA : WS_SO1BA) + fb * 64 + o] = acc;
    }
    for (int t = tid; t < 384; t += 256) {
        int n = t >> 7; int o = t & 127;
        float acc = vproj_b[o];
        for (int c = 0; c < 128; ++c) acc += level_embed[n * 128 + c] * vproj_w[o * 128 + c];
        ws[WS_VB + t] = acc;
    }
    if (tid < 48) {
        int b = tid / 12; int n = (tid / 4) % 3; int hh = tid & 3;
        float ad = fabsf(rel_scalar[b * 3 + n]);
        float s = 1.0f / (1.0f + expf(-(ad * dts_w[hh] + dts_b[hh])));
        ws[WS_HS + tid] = 1.0f + 0.5f * s;
    }
    if (tid < 12) ws[WS_ABSDT + tid] = fabsf(rel_scalar[tid]);
}

// ============================================================
// K1: per-window offsets + attn branches (+softmax, coords, entropy)
// ============================================================
__global__ __launch_bounds__(256) void win_kernel(
    const float* __restrict__ query,
    const float* __restrict__ so1_w, const float* __restrict__ so2_w, const float* __restrict__ so2_b,
    const float* __restrict__ gno_g, const float* __restrict__ gno_b,
    const float* __restrict__ aw1_w, const float* __restrict__ aw2_w, const float* __restrict__ aw2_b,
    const float* __restrict__ gna_g, const float* __restrict__ gna_b,
    float* __restrict__ ws, float* __restrict__ out)
{
    __shared__ float sA[8192];     // 32KB: phase1 qf[c][pix]; later partials/stats + conv2 outputs
    __shared__ float sYso[4096];   // y1 so-path [64][64]
    __shared__ float sYaw[4096];   // y1 aw-path [64][64]

    int tid = threadIdx.x;
    int bw  = blockIdx.x;
    int b   = bw >> 8;
    int win = bw & 255;
    int wy = win >> 4, wx = win & 15;
    int fb = bw & 3;          // tile semantics: index = bw % B
    int pix = tid & 63;
    int og  = ufl(tid >> 6);  // wave id 0..3 (uniform)

    // ---- load q window into sA[c*64+pix] ----
    const float* qbase = query + ((size_t)b << 21);  // b*128*128*128
    for (int idx = tid; idx < 8192; idx += 256) {
        int c = idx >> 6, px = idx & 63;
        int gh = wy * 8 + (px >> 3), gw = wx * 8 + (px & 7);
        sA[idx] = qbase[(c << 14) + (gh << 7) + gw];
    }
    __syncthreads();

    // ---- so1 / aw1: 64x64 each, thread = (pix, 16 outputs) ----
    {
        float accs[16], acca[16];
#pragma unroll
        for (int k = 0; k < 16; ++k) { accs[k] = 0.f; acca[k] = 0.f; }
        for (int c = 0; c < 128; ++c) {
            float q = sA[(c << 6) + pix];
            const float* ws1 = so1_w + (og * 16) * 128 + c;
            const float* wa1 = aw1_w + (og * 16) * 128 + c;
#pragma unroll
            for (int k = 0; k < 16; ++k) {
                accs[k] += ws1[k * 128] * q;
                acca[k] += wa1[k * 128] * q;
            }
        }
        const float* ba_s = ws + WS_SO1BA + fb * 64;
        const float* ba_a = ws + WS_AW1BA + fb * 64;
#pragma unroll
        for (int k = 0; k < 16; ++k) {
            int o = og * 16 + k;
            sYso[(o << 6) + pix] = accs[k] + ba_s[o];
            sYaw[(o << 6) + pix] = acca[k] + ba_a[o];
        }
    }
    __syncthreads();  // qf dead; sY visible

    // ---- GroupNorm(so) ----
    {
        float s = 0.f, sq = 0.f;
        int base = tid * 16;
#pragma unroll
        for (int k = 0; k < 16; ++k) { float v = sYso[base + k]; s += v; sq += v * v; }
        sA[tid] = s; sA[256 + tid] = sq;
    }
    __syncthreads();
    if (tid < 8) {
        float s = 0.f, sq = 0.f;
        for (int k = 0; k < 32; ++k) { s += sA[tid * 32 + k]; sq += sA[256 + tid * 32 + k]; }
        float mu = s * (1.f / 512.f);
        float var = sq * (1.f / 512.f) - mu * mu;
        sA[512 + tid] = mu;
        sA[520 + tid] = 1.f / sqrtf(var + 1e-5f);
    }
    __syncthreads();
    {
        int base = tid * 16;
        int g = tid >> 5;     // group of this thread's 16-value slice
        int c = tid >> 2;     // channel of this slice (constant within slice)
        float mu = sA[512 + g], rs = sA[520 + g];
        float ga = gno_g[c], be = gno_b[c];
#pragma unroll
        for (int k = 0; k < 16; ++k) {
            float v = (sYso[base + k] - mu) * rs * ga + be;
            sYso[base + k] = fmaxf(v, 0.f);
        }
    }
    __syncthreads();

    // ---- so2: 96x64 -> offsets into sA[1024 + ch*64 + pix] ----
    {
        float acc[24];
#pragma unroll
        for (int k = 0; k < 24; ++k) acc[k] = 0.f;
        for (int c = 0; c < 64; ++c) {
            float y = sYso[(c << 6) + pix];
            const float* w = so2_w + (og * 24) * 64 + c;
#pragma unroll
            for (int k = 0; k < 24; ++k) acc[k] += w[k * 64] * y;
        }
#pragma unroll
        for (int k = 0; k < 24; ++k) {
            int ch = og * 24 + k;
            sA[1024 + (ch << 6) + pix] = acc[k] + so2_b[ch];
        }
    }
    __syncthreads();

    // ---- coords (reads offsets) + GroupNorm(aw) partials, same phase ----
    {
        int hh = og;
        int btrue = bw >> 8;
        float refx = (float)(pix & 7) * (1.f / 7.f);
        float refy = (float)(pix >> 3) * (1.f / 7.f);
        float* co = ws + WS_COORD + ((((size_t)bw * 64 + pix) * 4 + hh) * 24);
#pragma unroll
        for (int l = 0; l < 3; ++l) {
            float hs = ws[WS_HS + (btrue * 3 + l) * 4 + hh];
#pragma unroll
            for (int p = 0; p < 4; ++p) {
                int chx = ((hh * 3 + l) * 4 + p) * 2;
                float ox = sA[1024 + (chx << 6) + pix];
                float oy = sA[1024 + ((chx + 1) << 6) + pix];
                float x = fminf(fmaxf(refx + ox, 0.f), 1.f) * 2.f - 1.f;
                float y = fminf(fmaxf(refy + oy, 0.f), 1.f) * 2.f - 1.f;
                x = fminf(fmaxf(x * hs, -1.f), 1.f);
                y = fminf(fmaxf(y * hs, -1.f), 1.f);
                float ix = fminf(fmaxf(((x + 1.f) * 8.f - 1.f) * 0.5f, 0.f), 7.f);
                float iy = fminf(fmaxf(((y + 1.f) * 8.f - 1.f) * 0.5f, 0.f), 7.f);
                co[(l * 4 + p) * 2]     = ix;
                co[(l * 4 + p) * 2 + 1] = iy;
            }
        }
    }
    {
        float s = 0.f, sq = 0.f;
        int base = tid * 16;
#pragma unroll
        for (int k = 0; k < 16; ++k) { float v = sYaw[base + k]; s += v; sq += v * v; }
        sA[tid] = s; sA[256 + tid] = sq;
    }
    __syncthreads();
    if (tid < 8) {
        float s = 0.f, sq = 0.f;
        for (int k = 0; k < 32; ++k) { s += sA[tid * 32 + k]; sq += sA[256 + tid * 32 + k]; }
        float mu = s * (1.f / 512.f);
        float var = sq * (1.f / 512.f) - mu * mu;
        sA[512 + tid] = mu;
        sA[520 + tid] = 1.f / sqrtf(var + 1e-5f);
    }
    __syncthreads();
    {
        int base = tid * 16;
        int g = tid >> 5;
        int c = tid >> 2;
        float mu = sA[512 + g], rs = sA[520 + g];
        float ga = gna_g[c], be = gna_b[c];
#pragma unroll
        for (int k = 0; k < 16; ++k) {
            float v = (sYaw[base + k] - mu) * rs * ga + be;
            sYaw[base + k] = fmaxf(v, 0.f);
        }
    }
    __syncthreads();

    // ---- aw2: 48x64 -> attn_raw into sA[1024 + ch*64 + pix] ----
    {
        float acc[12];
#pragma unroll
        for (int k = 0; k < 12; ++k) acc[k] = 0.f;
        for (int c = 0; c < 64; ++c) {
            float y = sYaw[(c << 6) + pix];
            const float* w = aw2_w + (og * 12) * 64 + c;
#pragma unroll
            for (int k = 0; k < 12; ++k) acc[k] += w[k * 64] * y;
        }
        __syncthreads();  // coords phase fully done before overwrite (already synced above, safe)
#pragma unroll
        for (int k = 0; k < 12; ++k) {
            int ch = og * 12 + k;
            sA[1024 + (ch << 6) + pix] = acc[k] + aw2_b[ch];
        }
    }
    __syncthreads();

    // ---- softmax over 12 (levels*points) per (pix, head) + entropy ----
    {
        int hh = og;
        const float* ad = ws + WS_ABSDT + fb * 3;
        float lg[12];
        float m = -1e30f;
#pragma unroll
        for (int q = 0; q < 12; ++q) {
            float v = sA[1024 + (((hh * 12 + q)) << 6) + pix] - ad[q >> 2];
            lg[q] = v; m = fmaxf(m, v);
        }
        float sum = 0.f;
#pragma unroll
        for (int q = 0; q < 12; ++q) { lg[q] = expf(lg[q] - m); sum += lg[q]; }
        float inv = 1.f / sum;
        float* at = ws + WS_ATTN + ((((size_t)bw * 64 + pix) * 4 + hh) * 12);
        float hent = 0.f;
#pragma unroll
        for (int q = 0; q < 12; ++q) {
            float p = lg[q] * inv;
            at[q] = p;
            float pp = p + 1e-8f;
            hent -= pp * logf(pp);
        }
        sA[pix * 4 + hh] = hent;   // disjoint from attn_raw region
    }
    __syncthreads();
    if (tid < 64) {
        float e = 0.25f * (sA[tid * 4] + sA[tid * 4 + 1] + sA[tid * 4 + 2] + sA[tid * 4 + 3]);
        int gh = wy * 8 + (tid >> 3), gw = wx * 8 + (tid & 7);
        out[OUT_ENT + (b << 14) + (gh << 7) + gw] = e;
    }
}

// ============================================================
// K2: v_proj -> v_flat (N, BW, NH, pix, HD) with HD contiguous
// ============================================================
__global__ __launch_bounds__(256) void vproj_kernel(
    const float* __restrict__ values, const float* __restrict__ vproj_w,
    float* __restrict__ ws)
{
    __shared__ float vbuf[8192];
    int tid = threadIdx.x;
    int bid = blockIdx.x;
    int n = bid >> 10;
    int bw = bid & 1023;
    int b = bw >> 8; int win = bw & 255;
    int wy = win >> 4, wx = win & 15;
    const float* vbase = values + ((size_t)(b * 3 + n) << 21);
    for (int idx = tid; idx < 8192; idx += 256) {
        int c = idx >> 6, px = idx & 63;
        int gh = wy * 8 + (px >> 3), gw = wx * 8 + (px & 7);
        vbuf[idx] = vbase[(c << 14) + (gh << 7) + gw];
    }
    __syncthreads();
    int pix = tid & 63;
    int og = ufl(tid >> 6);
    float acc[32];
#pragma unroll
    for (int k = 0; k < 32; ++k) acc[k] = 0.f;
    for (int c = 0; c < 128; ++c) {
        float v = vbuf[(c << 6) + pix];
        const float* w = vproj_w + (og * 32) * 128 + c;
#pragma unroll
        for (int k = 0; k < 32; ++k) acc[k] += w[k * 128] * v;
    }
    const float* vb = ws + WS_VB + n * 128 + og * 32;
    float* outp = ws + WS_VFLAT + (((((size_t)n << 10) + bw) * 4 + og) * 2048) + (size_t)pix * 32;
#pragma unroll
    for (int k = 0; k < 32; ++k) outp[k] = acc[k] + vb[k];
}

// ============================================================
// K3: bilinear sample + head-weighted sum + oproj, write fused
//     lanes span HD -> 128B coalesced tap reads
// ============================================================
__global__ __launch_bounds__(256) void sample_kernel(
    const float* __restrict__ oproj_w, const float* __restrict__ oproj_b,
    const float* __restrict__ ws, float* __restrict__ out)
{
    __shared__ float ob[128 * 65];   // out[c][pix], stride 65 to avoid bank conflicts
    int tid = threadIdx.x;
    int bw = blockIdx.x;
    int b = bw >> 8; int win = bw & 255;
    int wy = win >> 4, wx = win & 15;
    int d  = tid & 31;
    int hh = (tid >> 5) & 3;
    int ph = tid >> 7;
    const float* vf = ws + WS_VFLAT;
    const float* at = ws + WS_ATTN;
    const float* co = ws + WS_COORD;

    for (int q = 0; q < 32; ++q) {
        int pix = ph * 32 + q;
        size_t aoff = (((size_t)bw * 64 + pix) * 4 + hh);
        const float* a12 = at + aoff * 12;
        const float* c24 = co + aoff * 24;
        float acc = 0.f;
#pragma unroll
        for (int l = 0; l < 3; ++l) {
            const float* vbase = vf + (((((size_t)l << 10) + bw) * 4 + hh) * 2048) + d;
#pragma unroll
            for (int p = 0; p < 4; ++p) {
                float ix = c24[(l * 4 + p) * 2];
                float iy = c24[(l * 4 + p) * 2 + 1];
                float a  = a12[l * 4 + p];
                float x0f = floorf(ix), y0f = floorf(iy);
                int x0 = (int)x0f, y0 = (int)y0f;
                float wxf = ix - x0f, wyf = iy - y0f;
                int x1 = x0 + 1; if (x1 > 7) x1 = 7;
                int y1 = y0 + 1; if (y1 > 7) y1 = 7;
                float v00 = vbase[(((y0 << 3) + x0) << 5)];
                float v01 = vbase[(((y0 << 3) + x1) << 5)];
                float v10 = vbase[(((y1 << 3) + x0) << 5)];
                float v11 = vbase[(((y1 << 3) + x1) << 5)];
                float top = v00 + (v01 - v00) * wxf;
                float bot = v10 + (v11 - v10) * wxf;
                acc += a * (top + (bot - top) * wyf);
            }
        }
        ob[(hh * 32 + d) * 65 + pix] = acc;
    }
    __syncthreads();

    // oproj: fused[o][pix] = oproj_w[o][:] . ob[:][pix] + b[o]
    int pix = tid & 63;
    int og = ufl(tid >> 6);
    float acc2[32];
#pragma unroll
    for (int k = 0; k < 32; ++k) acc2[k] = 0.f;
    for (int c = 0; c < 128; ++c) {
        float v = ob[c * 65 + pix];
        const float* w = oproj_w + (og * 32) * 128 + c;
#pragma unroll
        for (int k = 0; k < 32; ++k) acc2[k] += w[k * 128] * v;
    }
    int gh = wy * 8 + (pix >> 3), gw = wx * 8 + (pix & 7);
#pragma unroll
    for (int k = 0; k < 32; ++k) {
        int o = og * 32 + k;
        out[OUT_FUSED + ((size_t)(b * 128 + o) << 14) + (gh << 7) + gw] = acc2[k] + oproj_b[o];
    }
}

// ============================================================
// K4: conf head — 3x3 conv (128->32) + relu + 1x1 (32->1) + sigmoid
// ============================================================
__global__ __launch_bounds__(256) void conf_kernel(
    const float* __restrict__ fused, const float* __restrict__ conf1_w, const float* __restrict__ conf1_b,
    const float* __restrict__ conf2_w, const float* __restrict__ conf2_b,
    float* __restrict__ out)
{
    __shared__ float tile[8 * 324];   // 8 ch x 18 x 18 halo tile
    int tid = threadIdx.x;
    int bid = blockIdx.x;
    int b = bid >> 6;
    int t = bid & 63; int ty = t >> 3, tx = t & 7;
    int py = tid >> 4, px = tid & 15;
    int oy = ty * 16, ox = tx * 16;
    const float* fin = fused + ((size_t)b << 21);

    float acc[32];
#pragma unroll
    for (int k = 0; k < 32; ++k) acc[k] = 0.f;

    for (int ch = 0; ch < 16; ++ch) {
        __syncthreads();
        for (int idx = tid; idx < 2592; idx += 256) {
            int c8 = idx / 324;
            int rem = idx - c8 * 324;
            int r = rem / 18, cc = rem - r * 18;
            int gy = oy + r - 1, gx = ox + cc - 1;
            float v = 0.f;
            if (gy >= 0 && gy < 128 && gx >= 0 && gx < 128)
                v = fin[((size_t)(ch * 8 + c8) << 14) + (gy << 7) + gx];
            tile[idx] = v;
        }
        __syncthreads();
#pragma unroll
        for (int c8 = 0; c8 < 8; ++c8) {
#pragma unroll
            for (int dy = 0; dy < 3; ++dy) {
#pragma unroll
                for (int dx = 0; dx < 3; ++dx) {
                    float v = tile[c8 * 324 + (py + dy) * 18 + (px + dx)];
#pragma unroll
                    for (int k = 0; k < 32; ++k)
                        acc[k] += v * conf1_w[((k * 128 + ch * 8 + c8) * 3 + dy) * 3 + dx];
                }
            }
        }
    }
    float s = conf2_b[0];
#pragma unroll
    for (int k = 0; k < 32; ++k) s += fmaxf(acc[k], 0.f) * conf2_w[k];
    float cf = 1.f / (1.f + expf(-s));
    int gy = oy + py, gx = ox + px;
    out[OUT_CONF + (b << 14) + (gy << 7) + gx] = cf;
}

// ============================================================
extern "C" void kernel_launch(void* const* d_in, const int* in_sizes, int n_in,
                              void* d_out, int out_size, void* d_ws, size_t ws_size,
                              hipStream_t stream) {
    const float* query      = (const float*)d_in[0];
    const float* values     = (const float*)d_in[1];
    const float* rel_scalar = (const float*)d_in[2];
    const float* tgt_enc    = (const float*)d_in[3];
    const float* so1_w = (const float*)d_in[4];
    const float* so1_b = (const float*)d_in[5];
    const float* gno_g = (const float*)d_in[6];
    const float* gno_b = (const float*)d_in[7];
    const float* so2_w = (const float*)d_in[8];
    const float* so2_b = (const float*)d_in[9];
    const float* aw1_w = (const float*)d_in[10];
    const float* aw1_b = (const float*)d_in[11];
    const float* gna_g = (const float*)d_in[12];
    const float* gna_b = (const float*)d_in[13];
    const float* aw2_w = (const float*)d_in[14];
    const float* aw2_b = (const float*)d_in[15];
    const float* vproj_w = (const float*)d_in[16];
    const float* vproj_b = (const float*)d_in[17];
    const float* oproj_w = (const float*)d_in[18];
    const float* oproj_b = (const float*)d_in[19];
    const float* filmo_w = (const float*)d_in[20];
    const float* filmo_b = (const float*)d_in[21];
    const float* filma_w = (const float*)d_in[22];
    const float* filma_b = (const float*)d_in[23];
    const float* dts_w   = (const float*)d_in[24];
    const float* dts_b   = (const float*)d_in[25];
    const float* level_embed = (const float*)d_in[26];
    const float* conf1_w = (const float*)d_in[27];
    const float* conf1_b = (const float*)d_in[28];
    const float* conf2_w = (const float*)d_in[29];
    const float* conf2_b = (const float*)d_in[30];

    float* ws  = (float*)d_ws;
    float* out = (float*)d_out;

    prep_kernel<<<1, 256, 0, stream>>>(tgt_enc, filmo_w, filmo_b, filma_w, filma_b,
                                       so1_w, so1_b, aw1_w, aw1_b,
                                       vproj_w, vproj_b, level_embed,
                                       rel_scalar, dts_w, dts_b, ws);
    win_kernel<<<BWTOT, 256, 0, stream>>>(query, so1_w, so2_w, so2_b, gno_g, gno_b,
                                          aw1_w, aw2_w, aw2_b, gna_g, gna_b, ws, out);
    vproj_kernel<<<NVAL * BWTOT, 256, 0, stream>>>(values, vproj_w, ws);
    sample_kernel<<<BWTOT, 256, 0, stream>>>(oproj_w, oproj_b, ws, out);
    conf_kernel<<<NB * 64, 256, 0, stream>>>(out, conf1_w, conf1_b, conf2_w, conf2_b, out);
}

// Round 2
// 1095.891 us; speedup vs baseline: 2.2281x; 2.2281x over previous
//
#include <hip/hip_runtime.h>
#include <math.h>

// ---- problem constants ----
#define NB 4
#define NVAL 3
#define NC 128
#define NHW 128
#define NHEAD 4
#define NPOINT 4
#define NLVL 3
#define WSZ 8
#define HD 32
#define NWIN 256      // 16x16 windows
#define BWTOT 1024    // NB * NWIN
#define NPIX 64       // WSZ*WSZ

// ---- workspace layout (float offsets) ----
#define WS_SO1BA 0                        // 4*64
#define WS_AW1BA 256                      // 4*64
#define WS_VB    512                      // 3*128
#define WS_HS    896                      // 4*3*4
#define WS_ABSDT 944                      // 4*3
#define WS_COORD 1024                     // 1024*64*4*12*2 = 6291456
#define WS_ATTN  (1024 + 6291456)         // 1024*64*4*12 = 3145728
#define WS_VFLAT (1024 + 6291456 + 3145728) // 3*1024*4*64*32 = 25165824

// ---- output layout (float offsets) ----
#define OUT_FUSED 0
#define OUT_CONF  8388608                 // 4*128*128*128
#define OUT_ENT   (8388608 + 65536)

__device__ __forceinline__ int ufl(int x) { return __builtin_amdgcn_readfirstlane(x); }

// ============================================================
// K0: prep — film-folded biases, vproj level bias, hscale, |dt|
// ============================================================
__global__ __launch_bounds__(256) void prep_kernel(
    const float* __restrict__ tgt_enc, const float* __restrict__ filmo_w, const float* __restrict__ filmo_b,
    const float* __restrict__ filma_w, const float* __restrict__ filma_b,
    const float* __restrict__ so1_w, const float* __restrict__ so1_b,
    const float* __restrict__ aw1_w, const float* __restrict__ aw1_b,
    const float* __restrict__ vproj_w, const float* __restrict__ vproj_b,
    const float* __restrict__ level_embed,
    const float* __restrict__ rel_scalar, const float* __restrict__ dts_w, const float* __restrict__ dts_b,
    float* __restrict__ ws)
{
    __shared__ float film[1024];  // [which][b][c] = which*512 + b*128 + c
    int tid = threadIdx.x;
    for (int t = tid; t < 1024; t += 256) {
        int which = t >> 9; int b = (t >> 7) & 3; int c = t & 127;
        const float* fw = which ? filma_w : filmo_w;
        const float* fb = which ? filma_b : filmo_b;
        float acc = fb[c];
        for (int k = 0; k < 64; ++k) acc += tgt_enc[b * 64 + k] * fw[c * 64 + k];
        film[t] = acc;
    }
    __syncthreads();
    for (int t = tid; t < 512; t += 256) {
        int which = t >> 8; int fb = (t >> 6) & 3; int o = t & 63;
        const float* w  = which ? aw1_w : so1_w;
        const float* bb = which ? aw1_b : so1_b;
        const float* fm = &film[which * 512 + fb * 128];
        float acc = bb[o];
        for (int c = 0; c < 128; ++c) acc += w[o * 128 + c] * fm[c];
        ws[(which ? WS_AW1BA : WS_SO1BA) + fb * 64 + o] = acc;
    }
    for (int t = tid; t < 384; t += 256) {
        int n = t >> 7; int o = t & 127;
        float acc = vproj_b[o];
        for (int c = 0; c < 128; ++c) acc += level_embed[n * 128 + c] * vproj_w[o * 128 + c];
        ws[WS_VB + t] = acc;
    }
    if (tid < 48) {
        int b = tid / 12; int n = (tid / 4) % 3; int hh = tid & 3;
        float ad = fabsf(rel_scalar[b * 3 + n]);
        float s = 1.0f / (1.0f + expf(-(ad * dts_w[hh] + dts_b[hh])));
        ws[WS_HS + tid] = 1.0f + 0.5f * s;
    }
    if (tid < 12) ws[WS_ABSDT + tid] = fabsf(rel_scalar[tid]);
}

// ============================================================
// K1: per-window offsets + attn branches (+softmax, coords, entropy)
// ============================================================
__global__ __launch_bounds__(256) void win_kernel(
    const float* __restrict__ query,
    const float* __restrict__ so1_w, const float* __restrict__ so2_w, const float* __restrict__ so2_b,
    const float* __restrict__ gno_g, const float* __restrict__ gno_b,
    const float* __restrict__ aw1_w, const float* __restrict__ aw2_w, const float* __restrict__ aw2_b,
    const float* __restrict__ gna_g, const float* __restrict__ gna_b,
    float* __restrict__ ws, float* __restrict__ out)
{
    __shared__ float sA[8192];     // 32KB: phase1 qf[c][pix]; later partials/stats + conv2 outputs
    __shared__ float sYso[4096];   // y1 so-path [64][64]
    __shared__ float sYaw[4096];   // y1 aw-path [64][64]

    int tid = threadIdx.x;
    int bw  = blockIdx.x;
    int b   = bw >> 8;
    int win = bw & 255;
    int wy = win >> 4, wx = win & 15;
    int fb = bw & 3;          // tile semantics: index = bw % B
    int pix = tid & 63;
    int og  = ufl(tid >> 6);  // wave id 0..3 (uniform)

    // ---- load q window into sA[c*64+pix] ----
    const float* qbase = query + ((size_t)b << 21);  // b*128*128*128
    for (int idx = tid; idx < 8192; idx += 256) {
        int c = idx >> 6, px = idx & 63;
        int gh = wy * 8 + (px >> 3), gw = wx * 8 + (px & 7);
        sA[idx] = qbase[(c << 14) + (gh << 7) + gw];
    }
    __syncthreads();

    // ---- so1 / aw1: 64x64 each, thread = (pix, 16 outputs) ----
    {
        float accs[16], acca[16];
#pragma unroll
        for (int k = 0; k < 16; ++k) { accs[k] = 0.f; acca[k] = 0.f; }
        for (int c = 0; c < 128; ++c) {
            float q = sA[(c << 6) + pix];
            const float* ws1 = so1_w + (og * 16) * 128 + c;
            const float* wa1 = aw1_w + (og * 16) * 128 + c;
#pragma unroll
            for (int k = 0; k < 16; ++k) {
                accs[k] += ws1[k * 128] * q;
                acca[k] += wa1[k * 128] * q;
            }
        }
        const float* ba_s = ws + WS_SO1BA + fb * 64;
        const float* ba_a = ws + WS_AW1BA + fb * 64;
#pragma unroll
        for (int k = 0; k < 16; ++k) {
            int o = og * 16 + k;
            sYso[(o << 6) + pix] = accs[k] + ba_s[o];
            sYaw[(o << 6) + pix] = acca[k] + ba_a[o];
        }
    }
    __syncthreads();  // qf dead; sY visible

    // ---- GroupNorm(so) ----
    {
        float s = 0.f, sq = 0.f;
        int base = tid * 16;
#pragma unroll
        for (int k = 0; k < 16; ++k) { float v = sYso[base + k]; s += v; sq += v * v; }
        sA[tid] = s; sA[256 + tid] = sq;
    }
    __syncthreads();
    if (tid < 8) {
        float s = 0.f, sq = 0.f;
        for (int k = 0; k < 32; ++k) { s += sA[tid * 32 + k]; sq += sA[256 + tid * 32 + k]; }
        float mu = s * (1.f / 512.f);
        float var = sq * (1.f / 512.f) - mu * mu;
        sA[512 + tid] = mu;
        sA[520 + tid] = 1.f / sqrtf(var + 1e-5f);
    }
    __syncthreads();
    {
        int base = tid * 16;
        int g = tid >> 5;     // group of this thread's 16-value slice
        int c = tid >> 2;     // channel of this slice (constant within slice)
        float mu = sA[512 + g], rs = sA[520 + g];
        float ga = gno_g[c], be = gno_b[c];
#pragma unroll
        for (int k = 0; k < 16; ++k) {
            float v = (sYso[base + k] - mu) * rs * ga + be;
            sYso[base + k] = fmaxf(v, 0.f);
        }
    }
    __syncthreads();

    // ---- so2: 96x64 -> offsets into sA[1024 + ch*64 + pix] ----
    {
        float acc[24];
#pragma unroll
        for (int k = 0; k < 24; ++k) acc[k] = 0.f;
        for (int c = 0; c < 64; ++c) {
            float y = sYso[(c << 6) + pix];
            const float* w = so2_w + (og * 24) * 64 + c;
#pragma unroll
            for (int k = 0; k < 24; ++k) acc[k] += w[k * 64] * y;
        }
#pragma unroll
        for (int k = 0; k < 24; ++k) {
            int ch = og * 24 + k;
            sA[1024 + (ch << 6) + pix] = acc[k] + so2_b[ch];
        }
    }
    __syncthreads();

    // ---- coords (reads offsets) + GroupNorm(aw) partials, same phase ----
    {
        int hh = og;
        int btrue = bw >> 8;
        float refx = (float)(pix & 7) * (1.f / 7.f);
        float refy = (float)(pix >> 3) * (1.f / 7.f);
        float* co = ws + WS_COORD + ((((size_t)bw * 64 + pix) * 4 + hh) * 24);
#pragma unroll
        for (int l = 0; l < 3; ++l) {
            float hs = ws[WS_HS + (btrue * 3 + l) * 4 + hh];
#pragma unroll
            for (int p = 0; p < 4; ++p) {
                int chx = ((hh * 3 + l) * 4 + p) * 2;
                float ox = sA[1024 + (chx << 6) + pix];
                float oy = sA[1024 + ((chx + 1) << 6) + pix];
                float x = fminf(fmaxf(refx + ox, 0.f), 1.f) * 2.f - 1.f;
                float y = fminf(fmaxf(refy + oy, 0.f), 1.f) * 2.f - 1.f;
                x = fminf(fmaxf(x * hs, -1.f), 1.f);
                y = fminf(fmaxf(y * hs, -1.f), 1.f);
                float ix = fminf(fmaxf(((x + 1.f) * 8.f - 1.f) * 0.5f, 0.f), 7.f);
                float iy = fminf(fmaxf(((y + 1.f) * 8.f - 1.f) * 0.5f, 0.f), 7.f);
                co[(l * 4 + p) * 2]     = ix;
                co[(l * 4 + p) * 2 + 1] = iy;
            }
        }
    }
    {
        float s = 0.f, sq = 0.f;
        int base = tid * 16;
#pragma unroll
        for (int k = 0; k < 16; ++k) { float v = sYaw[base + k]; s += v; sq += v * v; }
        sA[tid] = s; sA[256 + tid] = sq;
    }
    __syncthreads();
    if (tid < 8) {
        float s = 0.f, sq = 0.f;
        for (int k = 0; k < 32; ++k) { s += sA[tid * 32 + k]; sq += sA[256 + tid * 32 + k]; }
        float mu = s * (1.f / 512.f);
        float var = sq * (1.f / 512.f) - mu * mu;
        sA[512 + tid] = mu;
        sA[520 + tid] = 1.f / sqrtf(var + 1e-5f);
    }
    __syncthreads();
    {
        int base = tid * 16;
        int g = tid >> 5;
        int c = tid >> 2;
        float mu = sA[512 + g], rs = sA[520 + g];
        float ga = gna_g[c], be = gna_b[c];
#pragma unroll
        for (int k = 0; k < 16; ++k) {
            float v = (sYaw[base + k] - mu) * rs * ga + be;
            sYaw[base + k] = fmaxf(v, 0.f);
        }
    }
    __syncthreads();

    // ---- aw2: 48x64 -> attn_raw into sA[1024 + ch*64 + pix] ----
    {
        float acc[12];
#pragma unroll
        for (int k = 0; k < 12; ++k) acc[k] = 0.f;
        for (int c = 0; c < 64; ++c) {
            float y = sYaw[(c << 6) + pix];
            const float* w = aw2_w + (og * 12) * 64 + c;
#pragma unroll
            for (int k = 0; k < 12; ++k) acc[k] += w[k * 64] * y;
        }
        __syncthreads();
#pragma unroll
        for (int k = 0; k < 12; ++k) {
            int ch = og * 12 + k;
            sA[1024 + (ch << 6) + pix] = acc[k] + aw2_b[ch];
        }
    }
    __syncthreads();

    // ---- softmax over 12 (levels*points) per (pix, head) + entropy ----
    {
        int hh = og;
        const float* ad = ws + WS_ABSDT + fb * 3;
        float lg[12];
        float m = -1e30f;
#pragma unroll
        for (int q = 0; q < 12; ++q) {
            float v = sA[1024 + (((hh * 12 + q)) << 6) + pix] - ad[q >> 2];
            lg[q] = v; m = fmaxf(m, v);
        }
        float sum = 0.f;
#pragma unroll
        for (int q = 0; q < 12; ++q) { lg[q] = expf(lg[q] - m); sum += lg[q]; }
        float inv = 1.f / sum;
        float* at = ws + WS_ATTN + ((((size_t)bw * 64 + pix) * 4 + hh) * 12);
        float hent = 0.f;
#pragma unroll
        for (int q = 0; q < 12; ++q) {
            float p = lg[q] * inv;
            at[q] = p;
            float pp = p + 1e-8f;
            hent -= pp * logf(pp);
        }
        sA[pix * 4 + hh] = hent;   // disjoint from attn_raw region
    }
    __syncthreads();
    if (tid < 64) {
        float e = 0.25f * (sA[tid * 4] + sA[tid * 4 + 1] + sA[tid * 4 + 2] + sA[tid * 4 + 3]);
        int gh = wy * 8 + (tid >> 3), gw = wx * 8 + (tid & 7);
        out[OUT_ENT + (b << 14) + (gh << 7) + gw] = e;
    }
}

// ============================================================
// K2: v_proj -> v_flat (N, BW, NH, pix, HD) with HD contiguous
// ============================================================
__global__ __launch_bounds__(256) void vproj_kernel(
    const float* __restrict__ values, const float* __restrict__ vproj_w,
    float* __restrict__ ws)
{
    __shared__ float vbuf[8192];
    int tid = threadIdx.x;
    int bid = blockIdx.x;
    int n = bid >> 10;
    int bw = bid & 1023;
    int b = bw >> 8; int win = bw & 255;
    int wy = win >> 4, wx = win & 15;
    const float* vbase = values + ((size_t)(b * 3 + n) << 21);
    for (int idx = tid; idx < 8192; idx += 256) {
        int c = idx >> 6, px = idx & 63;
        int gh = wy * 8 + (px >> 3), gw = wx * 8 + (px & 7);
        vbuf[idx] = vbase[(c << 14) + (gh << 7) + gw];
    }
    __syncthreads();
    int pix = tid & 63;
    int og = ufl(tid >> 6);
    float acc[32];
#pragma unroll
    for (int k = 0; k < 32; ++k) acc[k] = 0.f;
    for (int c = 0; c < 128; ++c) {
        float v = vbuf[(c << 6) + pix];
        const float* w = vproj_w + (og * 32) * 128 + c;
#pragma unroll
        for (int k = 0; k < 32; ++k) acc[k] += w[k * 128] * v;
    }
    const float* vb = ws + WS_VB + n * 128 + og * 32;
    float* outp = ws + WS_VFLAT + (((((size_t)n << 10) + bw) * 4 + og) * 2048) + (size_t)pix * 32;
#pragma unroll
    for (int k = 0; k < 32; ++k) outp[k] = acc[k] + vb[k];
}

// ============================================================
// K3: bilinear sample + head-weighted sum + oproj, write fused
//     lanes span HD -> 128B coalesced tap reads
// ============================================================
__global__ __launch_bounds__(256) void sample_kernel(
    const float* __restrict__ oproj_w, const float* __restrict__ oproj_b,
    const float* __restrict__ ws, float* __restrict__ out)
{
    __shared__ float ob[128 * 65];   // out[c][pix], stride 65 to avoid bank conflicts
    int tid = threadIdx.x;
    int bw = blockIdx.x;
    int b = bw >> 8; int win = bw & 255;
    int wy = win >> 4, wx = win & 15;
    int d  = tid & 31;
    int hh = (tid >> 5) & 3;
    int ph = tid >> 7;
    const float* vf = ws + WS_VFLAT;
    const float* at = ws + WS_ATTN;
    const float* co = ws + WS_COORD;

    for (int q = 0; q < 32; ++q) {
        int pix = ph * 32 + q;
        size_t aoff = (((size_t)bw * 64 + pix) * 4 + hh);
        const float* a12 = at + aoff * 12;
        const float* c24 = co + aoff * 24;
        float acc = 0.f;
#pragma unroll
        for (int l = 0; l < 3; ++l) {
            const float* vbase = vf + (((((size_t)l << 10) + bw) * 4 + hh) * 2048) + d;
#pragma unroll
            for (int p = 0; p < 4; ++p) {
                float ix = c24[(l * 4 + p) * 2];
                float iy = c24[(l * 4 + p) * 2 + 1];
                float a  = a12[l * 4 + p];
                float x0f = floorf(ix), y0f = floorf(iy);
                int x0 = (int)x0f, y0 = (int)y0f;
                float wxf = ix - x0f, wyf = iy - y0f;
                int x1 = x0 + 1; if (x1 > 7) x1 = 7;
                int y1 = y0 + 1; if (y1 > 7) y1 = 7;
                float v00 = vbase[(((y0 << 3) + x0) << 5)];
                float v01 = vbase[(((y0 << 3) + x1) << 5)];
                float v10 = vbase[(((y1 << 3) + x0) << 5)];
                float v11 = vbase[(((y1 << 3) + x1) << 5)];
                float top = v00 + (v01 - v00) * wxf;
                float bot = v10 + (v11 - v10) * wxf;
                acc += a * (top + (bot - top) * wyf);
            }
        }
        ob[(hh * 32 + d) * 65 + pix] = acc;
    }
    __syncthreads();

    // oproj: fused[o][pix] = oproj_w[o][:] . ob[:][pix] + b[o]
    int pix = tid & 63;
    int og = ufl(tid >> 6);
    float acc2[32];
#pragma unroll
    for (int k = 0; k < 32; ++k) acc2[k] = 0.f;
    for (int c = 0; c < 128; ++c) {
        float v = ob[c * 65 + pix];
        const float* w = oproj_w + (og * 32) * 128 + c;
#pragma unroll
        for (int k = 0; k < 32; ++k) acc2[k] += w[k * 128] * v;
    }
    int gh = wy * 8 + (pix >> 3), gw = wx * 8 + (pix & 7);
#pragma unroll
    for (int k = 0; k < 32; ++k) {
        int o = og * 32 + k;
        out[OUT_FUSED + ((size_t)(b * 128 + o) << 14) + (gh << 7) + gw] = acc2[k] + oproj_b[o];
    }
}

// ============================================================
// K4: conf head — 3x3 conv (128->32) + relu + 1x1 (32->1) + sigmoid
//     Restructured: 8x8 tiles (1024 blocks), 64 pix x 4 k-groups,
//     wave-uniform (scalar) weight loads, 64-ch LDS chunks stride-11.
// ============================================================
__global__ __launch_bounds__(256) void conf_kernel(
    const float* __restrict__ fused, const float* __restrict__ conf1_w, const float* __restrict__ conf1_b,
    const float* __restrict__ conf2_w, const float* __restrict__ conf2_b,
    float* __restrict__ out)
{
    __shared__ float tile[64 * 110];   // 64 ch x 10 rows x 11-col stride = 28.2 KB
    __shared__ float red[4][64];
    int tid = threadIdx.x;
    int bid = blockIdx.x;
    int b = bid >> 8;                   // 4 batches x 256 tiles
    int t = bid & 255; int ty = t >> 4, tx = t & 15;  // 16x16 grid of 8x8 tiles
    int pix = tid & 63;
    int kg  = ufl(tid >> 6);            // wave-uniform k-group 0..3 (8 out-ch each)
    int py = pix >> 3, px = pix & 7;
    int oy = ty * 8, ox = tx * 8;
    const float* fin = fused + ((size_t)b << 21);

    float acc[8];
#pragma unroll
    for (int j = 0; j < 8; ++j) acc[j] = 0.f;

    for (int cc = 0; cc < 2; ++cc) {
        __syncthreads();
        // stage 64 ch x 10x10 halo (zero-padded borders), store stride 11
        for (int idx = tid; idx < 6400; idx += 256) {
            int c = idx / 100;
            int rem = idx - c * 100;
            int r = rem / 10, col = rem - r * 10;
            int gy = oy + r - 1, gx = ox + col - 1;
            float v = 0.f;
            if (gy >= 0 && gy < 128 && gx >= 0 && gx < 128)
                v = fin[((size_t)(cc * 64 + c) << 14) + (gy << 7) + gx];
            tile[c * 110 + r * 11 + col] = v;
        }
        __syncthreads();
        for (int c = 0; c < 64; ++c) {
            float v[9];
#pragma unroll
            for (int dy = 0; dy < 3; ++dy)
#pragma unroll
                for (int dx = 0; dx < 3; ++dx)
                    v[dy * 3 + dx] = tile[c * 110 + (py + dy) * 11 + (px + dx)];
            // wave-uniform weight base -> scalar loads; conf1_w[k][c][3][3], k-stride 1152
            const float* wp = conf1_w + ufl((kg * 8 * 128 + (cc * 64 + c)) * 9);
#pragma unroll
            for (int j = 0; j < 8; ++j) {
#pragma unroll
                for (int tap = 0; tap < 9; ++tap)
                    acc[j] += v[tap] * wp[j * 1152 + tap];
            }
        }
    }
    // bias + relu + 1x1 partial for this k-group
    float s = 0.f;
#pragma unroll
    for (int j = 0; j < 8; ++j) {
        int k = kg * 8 + j;
        s += fmaxf(acc[j] + conf1_b[k], 0.f) * conf2_w[k];
    }
    red[kg][pix] = s;
    __syncthreads();
    if (tid < 64) {
        float tot = red[0][tid] + red[1][tid] + red[2][tid] + red[3][tid] + conf2_b[0];
        float cf = 1.f / (1.f + expf(-tot));
        int gy = oy + (tid >> 3), gx = ox + (tid & 7);
        out[OUT_CONF + (b << 14) + (gy << 7) + gx] = cf;
    }
}

// ============================================================
extern "C" void kernel_launch(void* const* d_in, const int* in_sizes, int n_in,
                              void* d_out, int out_size, void* d_ws, size_t ws_size,
                              hipStream_t stream) {
    const float* query      = (const float*)d_in[0];
    const float* values     = (const float*)d_in[1];
    const float* rel_scalar = (const float*)d_in[2];
    const float* tgt_enc    = (const float*)d_in[3];
    const float* so1_w = (const float*)d_in[4];
    const float* so1_b = (const float*)d_in[5];
    const float* gno_g = (const float*)d_in[6];
    const float* gno_b = (const float*)d_in[7];
    const float* so2_w = (const float*)d_in[8];
    const float* so2_b = (const float*)d_in[9];
    const float* aw1_w = (const float*)d_in[10];
    const float* aw1_b = (const float*)d_in[11];
    const float* aw2_w = (const float*)d_in[14];
    const float* aw2_b = (const float*)d_in[15];
    const float* gna_g = (const float*)d_in[12];
    const float* gna_b = (const float*)d_in[13];
    const float* vproj_w = (const float*)d_in[16];
    const float* vproj_b = (const float*)d_in[17];
    const float* oproj_w = (const float*)d_in[18];
    const float* oproj_b = (const float*)d_in[19];
    const float* filmo_w = (const float*)d_in[20];
    const float* filmo_b = (const float*)d_in[21];
    const float* filma_w = (const float*)d_in[22];
    const float* filma_b = (const float*)d_in[23];
    const float* dts_w   = (const float*)d_in[24];
    const float* dts_b   = (const float*)d_in[25];
    const float* level_embed = (const float*)d_in[26];
    const float* conf1_w = (const float*)d_in[27];
    const float* conf1_b = (const float*)d_in[28];
    const float* conf2_w = (const float*)d_in[29];
    const float* conf2_b = (const float*)d_in[30];

    float* ws  = (float*)d_ws;
    float* out = (float*)d_out;

    prep_kernel<<<1, 256, 0, stream>>>(tgt_enc, filmo_w, filmo_b, filma_w, filma_b,
                                       so1_w, so1_b, aw1_w, aw1_b,
                                       vproj_w, vproj_b, level_embed,
                                       rel_scalar, dts_w, dts_b, ws);
    win_kernel<<<BWTOT, 256, 0, stream>>>(query, so1_w, so2_w, so2_b, gno_g, gno_b,
                                          aw1_w, aw2_w, aw2_b, gna_g, gna_b, ws, out);
    vproj_kernel<<<NVAL * BWTOT, 256, 0, stream>>>(values, vproj_w, ws);
    sample_kernel<<<BWTOT, 256, 0, stream>>>(oproj_w, oproj_b, ws, out);
    conf_kernel<<<NB * 256, 256, 0, stream>>>(out, conf1_w, conf1_b, conf2_w, conf2_b, out);
}

// Round 3
// 720.106 us; speedup vs baseline: 3.3908x; 1.5218x over previous
//
#include <hip/hip_runtime.h>
#include <math.h>

// ---- problem constants ----
#define NB 4
#define NVAL 3
#define NC 128
#define NHW 128
#define NHEAD 4
#define NPOINT 4
#define NLVL 3
#define WSZ 8
#define HD 32
#define NWIN 256      // 16x16 windows
#define BWTOT 1024    // NB * NWIN
#define NPIX 64       // WSZ*WSZ

// ---- workspace layout (float offsets) ----
#define WS_SO1BA 0                        // 4*64
#define WS_AW1BA 256                      // 4*64
#define WS_VB    512                      // 3*128
#define WS_HS    896                      // 4*3*4
#define WS_ABSDT 944                      // 4*3
// transposed weights (wT[c][o])
#define WT_VP    1024                     // 128*128
#define WT_OP    17408                    // 128*128
#define WT_SO1   33792                    // 128*64
#define WT_AW1   41984                    // 128*64
#define WT_SO2   50176                    // 64*96
#define WT_AW2   56320                    // 64*48
#define WT_C1    59392                    // 128*32*9
#define WS_COORD 96256                    // 1024*64*4*12*2
#define WS_ATTN  (96256 + 6291456)        // 1024*64*4*12
#define WS_VFLAT (96256 + 6291456 + 3145728)

// ---- output layout (float offsets) ----
#define OUT_FUSED 0
#define OUT_CONF  8388608                 // 4*128*128*128
#define OUT_ENT   (8388608 + 65536)

__device__ __forceinline__ int ufl(int x) { return __builtin_amdgcn_readfirstlane(x); }

// ============================================================
// K0: prep — film-folded biases, vproj level bias, hscale, |dt|,
//     + weight transposes (blocks 1..64)
// ============================================================
__global__ __launch_bounds__(256) void prep_kernel(
    const float* __restrict__ tgt_enc, const float* __restrict__ filmo_w, const float* __restrict__ filmo_b,
    const float* __restrict__ filma_w, const float* __restrict__ filma_b,
    const float* __restrict__ so1_w, const float* __restrict__ so1_b,
    const float* __restrict__ aw1_w, const float* __restrict__ aw1_b,
    const float* __restrict__ so2_w, const float* __restrict__ aw2_w,
    const float* __restrict__ vproj_w, const float* __restrict__ vproj_b,
    const float* __restrict__ oproj_w, const float* __restrict__ conf1_w,
    const float* __restrict__ level_embed,
    const float* __restrict__ rel_scalar, const float* __restrict__ dts_w, const float* __restrict__ dts_b,
    float* __restrict__ ws)
{
    int tid = threadIdx.x;
    if (blockIdx.x == 0) {
        __shared__ float film[1024];  // [which][b][c]
        for (int t = tid; t < 1024; t += 256) {
            int which = t >> 9; int b = (t >> 7) & 3; int c = t & 127;
            const float* fw = which ? filma_w : filmo_w;
            const float* fb = which ? filma_b : filmo_b;
            float acc = fb[c];
            for (int k = 0; k < 64; ++k) acc += tgt_enc[b * 64 + k] * fw[c * 64 + k];
            film[t] = acc;
        }
        __syncthreads();
        for (int t = tid; t < 512; t += 256) {
            int which = t >> 8; int fb = (t >> 6) & 3; int o = t & 63;
            const float* w  = which ? aw1_w : so1_w;
            const float* bb = which ? aw1_b : so1_b;
            const float* fm = &film[which * 512 + fb * 128];
            float acc = bb[o];
            for (int c = 0; c < 128; ++c) acc += w[o * 128 + c] * fm[c];
            ws[(which ? WS_AW1BA : WS_SO1BA) + fb * 64 + o] = acc;
        }
        for (int t = tid; t < 384; t += 256) {
            int n = t >> 7; int o = t & 127;
            float acc = vproj_b[o];
            for (int c = 0; c < 128; ++c) acc += level_embed[n * 128 + c] * vproj_w[o * 128 + c];
            ws[WS_VB + t] = acc;
        }
        if (tid < 48) {
            int b = tid / 12; int n = (tid / 4) % 3; int hh = tid & 3;
            float ad = fabsf(rel_scalar[b * 3 + n]);
            float s = 1.0f / (1.0f + expf(-(ad * dts_w[hh] + dts_b[hh])));
            ws[WS_HS + tid] = 1.0f + 0.5f * s;
        }
        if (tid < 12) ws[WS_ABSDT + tid] = fabsf(rel_scalar[tid]);
    } else {
        int base = (blockIdx.x - 1) * 256 + tid;   // 0..16383
        {
            int c = base >> 7, o = base & 127;
            ws[WT_VP + base] = vproj_w[o * 128 + c];
            ws[WT_OP + base] = oproj_w[o * 128 + c];
        }
        if (base < 8192) {
            int c = base >> 6, o = base & 63;
            ws[WT_SO1 + base] = so1_w[o * 128 + c];
            ws[WT_AW1 + base] = aw1_w[o * 128 + c];
        }
        if (base < 6144) {
            int c = base / 96, o = base - c * 96;
            ws[WT_SO2 + base] = so2_w[o * 64 + c];
        }
        if (base < 3072) {
            int c = base / 48, o = base - c * 48;
            ws[WT_AW2 + base] = aw2_w[o * 64 + c];
        }
        for (int t = base; t < 36864; t += 16384) {
            int c = t / 288; int rem = t - c * 288; int k = rem / 9, tap = rem - k * 9;
            ws[WT_C1 + t] = conf1_w[(k * 128 + c) * 9 + tap];
        }
    }
}

// ============================================================
// K1: per-window offsets + attn branches (+softmax, coords, entropy)
// ============================================================
__global__ __launch_bounds__(256) void win_kernel(
    const float* __restrict__ query,
    const float* __restrict__ so2_b,
    const float* __restrict__ gno_g, const float* __restrict__ gno_b,
    const float* __restrict__ aw2_b,
    const float* __restrict__ gna_g, const float* __restrict__ gna_b,
    float* __restrict__ ws, float* __restrict__ out)
{
    __shared__ float sA[8192];     // 32KB
    __shared__ float sYso[4096];   // y1 so-path [64][64]
    __shared__ float sYaw[4096];   // y1 aw-path [64][64]

    int tid = threadIdx.x;
    int bw  = blockIdx.x;
    int b   = bw >> 8;
    int win = bw & 255;
    int wy = win >> 4, wx = win & 15;
    int fb = bw & 3;          // tile semantics: index = bw % B
    int pix = tid & 63;
    int og  = ufl(tid >> 6);  // wave id 0..3 (uniform)

    // ---- load q window into sA[c*64+pix] ----
    const float* qbase = query + ((size_t)b << 21);
    for (int idx = tid; idx < 2048; idx += 256) {
        int c = idx >> 4, j = idx & 15;
        int row = j >> 1, half = j & 1;
        int gh = wy * 8 + row, gw0 = wx * 8 + half * 4;
        const float4 v = *(const float4*)(qbase + (c << 14) + (gh << 7) + gw0);
        *(float4*)(&sA[(c << 6) + (row << 3) + half * 4]) = v;
    }
    __syncthreads();

    // ---- so1 / aw1: 64x64 each, thread = (pix, 16 outputs) ----
    {
        float accs[16], acca[16];
#pragma unroll
        for (int k = 0; k < 16; ++k) { accs[k] = 0.f; acca[k] = 0.f; }
#pragma unroll 4
        for (int c = 0; c < 128; ++c) {
            float q = sA[(c << 6) + pix];
            const float* ws1 = ws + WT_SO1 + c * 64 + og * 16;
            const float* wa1 = ws + WT_AW1 + c * 64 + og * 16;
#pragma unroll
            for (int k = 0; k < 16; ++k) {
                accs[k] += ws1[k] * q;
                acca[k] += wa1[k] * q;
            }
        }
        const float* ba_s = ws + WS_SO1BA + fb * 64;
        const float* ba_a = ws + WS_AW1BA + fb * 64;
#pragma unroll
        for (int k = 0; k < 16; ++k) {
            int o = og * 16 + k;
            sYso[(o << 6) + pix] = accs[k] + ba_s[o];
            sYaw[(o << 6) + pix] = acca[k] + ba_a[o];
        }
    }
    __syncthreads();

    // ---- GroupNorm(so) ----
    {
        float s = 0.f, sq = 0.f;
        int base = tid * 16;
#pragma unroll
        for (int k = 0; k < 16; ++k) { float v = sYso[base + k]; s += v; sq += v * v; }
        sA[tid] = s; sA[256 + tid] = sq;
    }
    __syncthreads();
    if (tid < 8) {
        float s = 0.f, sq = 0.f;
        for (int k = 0; k < 32; ++k) { s += sA[tid * 32 + k]; sq += sA[256 + tid * 32 + k]; }
        float mu = s * (1.f / 512.f);
        float var = sq * (1.f / 512.f) - mu * mu;
        sA[512 + tid] = mu;
        sA[520 + tid] = 1.f / sqrtf(var + 1e-5f);
    }
    __syncthreads();
    {
        int base = tid * 16;
        int g = tid >> 5;
        int c = tid >> 2;
        float mu = sA[512 + g], rs = sA[520 + g];
        float ga = gno_g[c], be = gno_b[c];
#pragma unroll
        for (int k = 0; k < 16; ++k) {
            float v = (sYso[base + k] - mu) * rs * ga + be;
            sYso[base + k] = fmaxf(v, 0.f);
        }
    }
    __syncthreads();

    // ---- so2: 96x64 -> offsets into sA[1024 + ch*64 + pix] ----
    {
        float acc[24];
#pragma unroll
        for (int k = 0; k < 24; ++k) acc[k] = 0.f;
#pragma unroll 4
        for (int c = 0; c < 64; ++c) {
            float y = sYso[(c << 6) + pix];
            const float* w = ws + WT_SO2 + c * 96 + og * 24;
#pragma unroll
            for (int k = 0; k < 24; ++k) acc[k] += w[k] * y;
        }
#pragma unroll
        for (int k = 0; k < 24; ++k) {
            int ch = og * 24 + k;
            sA[1024 + (ch << 6) + pix] = acc[k] + so2_b[ch];
        }
    }
    __syncthreads();

    // ---- coords (reads offsets) + GroupNorm(aw) partials ----
    {
        int hh = og;
        int btrue = bw >> 8;
        float refx = (float)(pix & 7) * (1.f / 7.f);
        float refy = (float)(pix >> 3) * (1.f / 7.f);
        float* co = ws + WS_COORD + ((((size_t)bw * 64 + pix) * 4 + hh) * 24);
#pragma unroll
        for (int l = 0; l < 3; ++l) {
            float hs = ws[WS_HS + (btrue * 3 + l) * 4 + hh];
#pragma unroll
            for (int p = 0; p < 4; ++p) {
                int chx = ((hh * 3 + l) * 4 + p) * 2;
                float ox = sA[1024 + (chx << 6) + pix];
                float oy = sA[1024 + ((chx + 1) << 6) + pix];
                float x = fminf(fmaxf(refx + ox, 0.f), 1.f) * 2.f - 1.f;
                float y = fminf(fmaxf(refy + oy, 0.f), 1.f) * 2.f - 1.f;
                x = fminf(fmaxf(x * hs, -1.f), 1.f);
                y = fminf(fmaxf(y * hs, -1.f), 1.f);
                float ix = fminf(fmaxf(((x + 1.f) * 8.f - 1.f) * 0.5f, 0.f), 7.f);
                float iy = fminf(fmaxf(((y + 1.f) * 8.f - 1.f) * 0.5f, 0.f), 7.f);
                co[(l * 4 + p) * 2]     = ix;
                co[(l * 4 + p) * 2 + 1] = iy;
            }
        }
    }
    {
        float s = 0.f, sq = 0.f;
        int base = tid * 16;
#pragma unroll
        for (int k = 0; k < 16; ++k) { float v = sYaw[base + k]; s += v; sq += v * v; }
        sA[tid] = s; sA[256 + tid] = sq;
    }
    __syncthreads();
    if (tid < 8) {
        float s = 0.f, sq = 0.f;
        for (int k = 0; k < 32; ++k) { s += sA[tid * 32 + k]; sq += sA[256 + tid * 32 + k]; }
        float mu = s * (1.f / 512.f);
        float var = sq * (1.f / 512.f) - mu * mu;
        sA[512 + tid] = mu;
        sA[520 + tid] = 1.f / sqrtf(var + 1e-5f);
    }
    __syncthreads();
    {
        int base = tid * 16;
        int g = tid >> 5;
        int c = tid >> 2;
        float mu = sA[512 + g], rs = sA[520 + g];
        float ga = gna_g[c], be = gna_b[c];
#pragma unroll
        for (int k = 0; k < 16; ++k) {
            float v = (sYaw[base + k] - mu) * rs * ga + be;
            sYaw[base + k] = fmaxf(v, 0.f);
        }
    }
    __syncthreads();

    // ---- aw2: 48x64 -> attn_raw into sA[1024 + ch*64 + pix] ----
    {
        float acc[12];
#pragma unroll
        for (int k = 0; k < 12; ++k) acc[k] = 0.f;
#pragma unroll 4
        for (int c = 0; c < 64; ++c) {
            float y = sYaw[(c << 6) + pix];
            const float* w = ws + WT_AW2 + c * 48 + og * 12;
#pragma unroll
            for (int k = 0; k < 12; ++k) acc[k] += w[k] * y;
        }
        __syncthreads();
#pragma unroll
        for (int k = 0; k < 12; ++k) {
            int ch = og * 12 + k;
            sA[1024 + (ch << 6) + pix] = acc[k] + aw2_b[ch];
        }
    }
    __syncthreads();

    // ---- softmax over 12 per (pix, head) + entropy ----
    {
        int hh = og;
        const float* ad = ws + WS_ABSDT + fb * 3;
        float lg[12];
        float m = -1e30f;
#pragma unroll
        for (int q = 0; q < 12; ++q) {
            float v = sA[1024 + (((hh * 12 + q)) << 6) + pix] - ad[q >> 2];
            lg[q] = v; m = fmaxf(m, v);
        }
        float sum = 0.f;
#pragma unroll
        for (int q = 0; q < 12; ++q) { lg[q] = expf(lg[q] - m); sum += lg[q]; }
        float inv = 1.f / sum;
        float* at = ws + WS_ATTN + ((((size_t)bw * 64 + pix) * 4 + hh) * 12);
        float hent = 0.f;
#pragma unroll
        for (int q = 0; q < 12; ++q) {
            float p = lg[q] * inv;
            at[q] = p;
            float pp = p + 1e-8f;
            hent -= pp * logf(pp);
        }
        sA[pix * 4 + hh] = hent;
    }
    __syncthreads();
    if (tid < 64) {
        float e = 0.25f * (sA[tid * 4] + sA[tid * 4 + 1] + sA[tid * 4 + 2] + sA[tid * 4 + 3]);
        int gh = wy * 8 + (tid >> 3), gw = wx * 8 + (tid & 7);
        out[OUT_ENT + (b << 14) + (gh << 7) + gw] = e;
    }
}

// ============================================================
// K2: v_proj -> v_flat (N, BW, NH, pix, HD), HD contiguous
//     transposed weights (contiguous scalar loads) +
//     LDS-transpose for fully coalesced float4 stores
// ============================================================
__global__ __launch_bounds__(256) void vproj_kernel(
    const float* __restrict__ values, float* __restrict__ ws)
{
    __shared__ float sbuf[8448];   // staging [128][64]; then transpose [256 rows][33]
    int tid = threadIdx.x;
    int bid = blockIdx.x;
    int n = bid >> 10;
    int bw = bid & 1023;
    int b = bw >> 8; int win = bw & 255;
    int wy = win >> 4, wx = win & 15;
    const float* vbase = values + ((size_t)(b * 3 + n) << 21);
    for (int idx = tid; idx < 2048; idx += 256) {
        int c = idx >> 4, j = idx & 15;
        int row = j >> 1, half = j & 1;
        int gh = wy * 8 + row, gw0 = wx * 8 + half * 4;
        const float4 v = *(const float4*)(vbase + (c << 14) + (gh << 7) + gw0);
        *(float4*)(&sbuf[(c << 6) + (row << 3) + half * 4]) = v;
    }
    int pix = tid & 63;
    int og = ufl(tid >> 6);
    float vbr[32];
    {
        const float* vb = ws + WS_VB + n * 128 + og * 32;
#pragma unroll
        for (int k = 0; k < 32; ++k) vbr[k] = vb[k];
    }
    __syncthreads();
    float acc[32];
#pragma unroll
    for (int k = 0; k < 32; ++k) acc[k] = 0.f;
#pragma unroll 4
    for (int c = 0; c < 128; ++c) {
        float v = sbuf[(c << 6) + pix];
        const float* w = ws + WT_VP + c * 128 + og * 32;
#pragma unroll
        for (int k = 0; k < 32; ++k) acc[k] += w[k] * v;
    }
    __syncthreads();   // done reading staging
    int row = (og << 6) + pix;
#pragma unroll
    for (int k = 0; k < 32; ++k) sbuf[row * 33 + k] = acc[k] + vbr[k];
    __syncthreads();
    float* base2 = ws + WS_VFLAT + ((((size_t)n << 10) + bw) << 13);
#pragma unroll
    for (int i = 0; i < 8; ++i) {
        int f4 = (i * 256 + tid) * 4;
        int r = f4 >> 5, k = f4 & 31;
        float4 v = make_float4(sbuf[r * 33 + k], sbuf[r * 33 + k + 1],
                               sbuf[r * 33 + k + 2], sbuf[r * 33 + k + 3]);
        *(float4*)(base2 + f4) = v;
    }
}

// ============================================================
// K3: bilinear sample + head-weighted sum + oproj, write fused
// ============================================================
__global__ __launch_bounds__(256) void sample_kernel(
    const float* __restrict__ oproj_b,
    float* __restrict__ ws, float* __restrict__ out)
{
    __shared__ float ob[128 * 65];   // out[c][pix], stride 65
    int tid = threadIdx.x;
    int bw = blockIdx.x;
    int b = bw >> 8; int win = bw & 255;
    int wy = win >> 4, wx = win & 15;
    int d  = tid & 31;
    int hh = (tid >> 5) & 3;
    int ph = tid >> 7;
    const float* vf = ws + WS_VFLAT;
    const float* at = ws + WS_ATTN;
    const float* co = ws + WS_COORD;

    for (int q = 0; q < 32; ++q) {
        int pix = ph * 32 + q;
        size_t aoff = (((size_t)bw * 64 + pix) * 4 + hh);
        const float* a12 = at + aoff * 12;
        const float* c24 = co + aoff * 24;
        float acc = 0.f;
#pragma unroll
        for (int l = 0; l < 3; ++l) {
            const float* vbase = vf + (((((size_t)l << 10) + bw) * 4 + hh) * 2048) + d;
#pragma unroll
            for (int p = 0; p < 4; ++p) {
                float ix = c24[(l * 4 + p) * 2];
                float iy = c24[(l * 4 + p) * 2 + 1];
                float a  = a12[l * 4 + p];
                float x0f = floorf(ix), y0f = floorf(iy);
                int x0 = (int)x0f, y0 = (int)y0f;
                float wxf = ix - x0f, wyf = iy - y0f;
                int x1 = x0 + 1; if (x1 > 7) x1 = 7;
                int y1 = y0 + 1; if (y1 > 7) y1 = 7;
                float v00 = vbase[(((y0 << 3) + x0) << 5)];
                float v01 = vbase[(((y0 << 3) + x1) << 5)];
                float v10 = vbase[(((y1 << 3) + x0) << 5)];
                float v11 = vbase[(((y1 << 3) + x1) << 5)];
                float top = v00 + (v01 - v00) * wxf;
                float bot = v10 + (v11 - v10) * wxf;
                acc += a * (top + (bot - top) * wyf);
            }
        }
        ob[(hh * 32 + d) * 65 + pix] = acc;
    }
    __syncthreads();

    // oproj (transposed weights)
    int pix = tid & 63;
    int og = ufl(tid >> 6);
    float acc2[32];
#pragma unroll
    for (int k = 0; k < 32; ++k) acc2[k] = 0.f;
#pragma unroll 4
    for (int c = 0; c < 128; ++c) {
        float v = ob[c * 65 + pix];
        const float* w = ws + WT_OP + c * 128 + og * 32;
#pragma unroll
        for (int k = 0; k < 32; ++k) acc2[k] += w[k] * v;
    }
    int gh = wy * 8 + (pix >> 3), gw = wx * 8 + (pix & 7);
#pragma unroll
    for (int k = 0; k < 32; ++k) {
        int o = og * 32 + k;
        out[OUT_FUSED + ((size_t)(b * 128 + o) << 14) + (gh << 7) + gw] = acc2[k] + oproj_b[o];
    }
}

// ============================================================
// K4: conf head — 3x3 conv (128->32) + relu + 1x1 (32->1) + sigmoid
// ============================================================
__global__ __launch_bounds__(256) void conf_kernel(
    const float* __restrict__ fused, const float* __restrict__ conf1_b,
    const float* __restrict__ conf2_w, const float* __restrict__ conf2_b,
    const float* __restrict__ ws, float* __restrict__ out)
{
    __shared__ float tile[64 * 110];   // 64 ch x 10 rows x 11-col stride
    __shared__ float red[4][64];
    int tid = threadIdx.x;
    int bid = blockIdx.x;
    int b = bid >> 8;
    int t = bid & 255; int ty = t >> 4, tx = t & 15;
    int pix = tid & 63;
    int kg  = ufl(tid >> 6);
    int py = pix >> 3, px = pix & 7;
    int oy = ty * 8, ox = tx * 8;
    const float* fin = fused + ((size_t)b << 21);

    float acc[8];
#pragma unroll
    for (int j = 0; j < 8; ++j) acc[j] = 0.f;

    for (int cc = 0; cc < 2; ++cc) {
        __syncthreads();
        for (int idx = tid; idx < 6400; idx += 256) {
            int c = idx / 100;
            int rem = idx - c * 100;
            int r = rem / 10, col = rem - r * 10;
            int gy = oy + r - 1, gx = ox + col - 1;
            float v = 0.f;
            if (gy >= 0 && gy < 128 && gx >= 0 && gx < 128)
                v = fin[((size_t)(cc * 64 + c) << 14) + (gy << 7) + gx];
            tile[c * 110 + r * 11 + col] = v;
        }
        __syncthreads();
        for (int c = 0; c < 64; ++c) {
            float v[9];
#pragma unroll
            for (int dy = 0; dy < 3; ++dy)
#pragma unroll
                for (int dx = 0; dx < 3; ++dx)
                    v[dy * 3 + dx] = tile[c * 110 + (py + dy) * 11 + (px + dx)];
            // transposed conf1: [cin][32 k][9 taps] — contiguous 72 floats per (cin,kg)
            const float* wp = ws + WT_C1 + ufl((cc * 64 + c) * 288 + kg * 72);
#pragma unroll
            for (int j = 0; j < 8; ++j) {
#pragma unroll
                for (int tap = 0; tap < 9; ++tap)
                    acc[j] += v[tap] * wp[j * 9 + tap];
            }
        }
    }
    float s = 0.f;
#pragma unroll
    for (int j = 0; j < 8; ++j) {
        int k = kg * 8 + j;
        s += fmaxf(acc[j] + conf1_b[k], 0.f) * conf2_w[k];
    }
    red[kg][pix] = s;
    __syncthreads();
    if (tid < 64) {
        float tot = red[0][tid] + red[1][tid] + red[2][tid] + red[3][tid] + conf2_b[0];
        float cf = 1.f / (1.f + expf(-tot));
        int gy = oy + (tid >> 3), gx = ox + (tid & 7);
        out[OUT_CONF + (b << 14) + (gy << 7) + gx] = cf;
    }
}

// ============================================================
extern "C" void kernel_launch(void* const* d_in, const int* in_sizes, int n_in,
                              void* d_out, int out_size, void* d_ws, size_t ws_size,
                              hipStream_t stream) {
    const float* query      = (const float*)d_in[0];
    const float* values     = (const float*)d_in[1];
    const float* rel_scalar = (const float*)d_in[2];
    const float* tgt_enc    = (const float*)d_in[3];
    const float* so1_w = (const float*)d_in[4];
    const float* so1_b = (const float*)d_in[5];
    const float* gno_g = (const float*)d_in[6];
    const float* gno_b = (const float*)d_in[7];
    const float* so2_w = (const float*)d_in[8];
    const float* so2_b = (const float*)d_in[9];
    const float* aw1_w = (const float*)d_in[10];
    const float* aw1_b = (const float*)d_in[11];
    const float* gna_g = (const float*)d_in[12];
    const float* gna_b = (const float*)d_in[13];
    const float* aw2_w = (const float*)d_in[14];
    const float* aw2_b = (const float*)d_in[15];
    const float* vproj_w = (const float*)d_in[16];
    const float* vproj_b = (const float*)d_in[17];
    const float* oproj_w = (const float*)d_in[18];
    const float* oproj_b = (const float*)d_in[19];
    const float* filmo_w = (const float*)d_in[20];
    const float* filmo_b = (const float*)d_in[21];
    const float* filma_w = (const float*)d_in[22];
    const float* filma_b = (const float*)d_in[23];
    const float* dts_w   = (const float*)d_in[24];
    const float* dts_b   = (const float*)d_in[25];
    const float* level_embed = (const float*)d_in[26];
    const float* conf1_w = (const float*)d_in[27];
    const float* conf1_b = (const float*)d_in[28];
    const float* conf2_w = (const float*)d_in[29];
    const float* conf2_b = (const float*)d_in[30];

    float* ws  = (float*)d_ws;
    float* out = (float*)d_out;

    prep_kernel<<<65, 256, 0, stream>>>(tgt_enc, filmo_w, filmo_b, filma_w, filma_b,
                                        so1_w, so1_b, aw1_w, aw1_b,
                                        so2_w, aw2_w,
                                        vproj_w, vproj_b, oproj_w, conf1_w,
                                        level_embed, rel_scalar, dts_w, dts_b, ws);
    win_kernel<<<BWTOT, 256, 0, stream>>>(query, so2_b, gno_g, gno_b,
                                          aw2_b, gna_g, gna_b, ws, out);
    vproj_kernel<<<NVAL * BWTOT, 256, 0, stream>>>(values, ws);
    sample_kernel<<<BWTOT, 256, 0, stream>>>(oproj_b, ws, out);
    conf_kernel<<<NB * 256, 256, 0, stream>>>(out, conf1_b, conf2_w, conf2_b, ws, out);
}

// Round 4
// 700.502 us; speedup vs baseline: 3.4857x; 1.0280x over previous
//
#include <hip/hip_runtime.h>
#include <math.h>

// ---- problem constants ----
#define NB 4
#define NVAL 3
#define NC 128
#define NHW 128
#define NHEAD 4
#define NPOINT 4
#define NLVL 3
#define WSZ 8
#define HD 32
#define NWIN 256      // 16x16 windows
#define BWTOT 1024    // NB * NWIN
#define NPIX 64       // WSZ*WSZ

// ---- workspace layout (float offsets) ----
#define WS_SO1BA 0                        // 4*64
#define WS_AW1BA 256                      // 4*64
#define WS_VB    512                      // 3*128
#define WS_HS    896                      // 4*3*4
#define WS_ABSDT 944                      // 4*3
// transposed weights (wT[c][o])
#define WT_VP    1024                     // 128*128
#define WT_OP    17408                    // 128*128
#define WT_SO1   33792                    // 128*64
#define WT_AW1   41984                    // 128*64
#define WT_SO2   50176                    // 64*96
#define WT_AW2   56320                    // 64*48
#define WT_C1    59392                    // 128*32*9
#define WS_COORD 96256                    // 1024*64*4*12*2
#define WS_ATTN  (96256 + 6291456)        // 1024*64*4*12
#define WS_VFLAT (96256 + 6291456 + 3145728)

// ---- output layout (float offsets) ----
#define OUT_FUSED 0
#define OUT_CONF  8388608                 // 4*128*128*128
#define OUT_ENT   (8388608 + 65536)

__device__ __forceinline__ int ufl(int x) { return __builtin_amdgcn_readfirstlane(x); }

// ============================================================
// K0: prep — film-folded biases, vproj level bias, hscale, |dt|,
//     + weight transposes (blocks 1..64)
// ============================================================
__global__ __launch_bounds__(256) void prep_kernel(
    const float* __restrict__ tgt_enc, const float* __restrict__ filmo_w, const float* __restrict__ filmo_b,
    const float* __restrict__ filma_w, const float* __restrict__ filma_b,
    const float* __restrict__ so1_w, const float* __restrict__ so1_b,
    const float* __restrict__ aw1_w, const float* __restrict__ aw1_b,
    const float* __restrict__ so2_w, const float* __restrict__ aw2_w,
    const float* __restrict__ vproj_w, const float* __restrict__ vproj_b,
    const float* __restrict__ oproj_w, const float* __restrict__ conf1_w,
    const float* __restrict__ level_embed,
    const float* __restrict__ rel_scalar, const float* __restrict__ dts_w, const float* __restrict__ dts_b,
    float* __restrict__ ws)
{
    int tid = threadIdx.x;
    if (blockIdx.x == 0) {
        __shared__ float film[1024];  // [which][b][c]
        for (int t = tid; t < 1024; t += 256) {
            int which = t >> 9; int b = (t >> 7) & 3; int c = t & 127;
            const float* fw = which ? filma_w : filmo_w;
            const float* fb = which ? filma_b : filmo_b;
            float acc = fb[c];
            for (int k = 0; k < 64; ++k) acc += tgt_enc[b * 64 + k] * fw[c * 64 + k];
            film[t] = acc;
        }
        __syncthreads();
        for (int t = tid; t < 512; t += 256) {
            int which = t >> 8; int fb = (t >> 6) & 3; int o = t & 63;
            const float* w  = which ? aw1_w : so1_w;
            const float* bb = which ? aw1_b : so1_b;
            const float* fm = &film[which * 512 + fb * 128];
            float acc = bb[o];
            for (int c = 0; c < 128; ++c) acc += w[o * 128 + c] * fm[c];
            ws[(which ? WS_AW1BA : WS_SO1BA) + fb * 64 + o] = acc;
        }
        for (int t = tid; t < 384; t += 256) {
            int n = t >> 7; int o = t & 127;
            float acc = vproj_b[o];
            for (int c = 0; c < 128; ++c) acc += level_embed[n * 128 + c] * vproj_w[o * 128 + c];
            ws[WS_VB + t] = acc;
        }
        if (tid < 48) {
            int b = tid / 12; int n = (tid / 4) % 3; int hh = tid & 3;
            float ad = fabsf(rel_scalar[b * 3 + n]);
            float s = 1.0f / (1.0f + expf(-(ad * dts_w[hh] + dts_b[hh])));
            ws[WS_HS + tid] = 1.0f + 0.5f * s;
        }
        if (tid < 12) ws[WS_ABSDT + tid] = fabsf(rel_scalar[tid]);
    } else {
        int base = (blockIdx.x - 1) * 256 + tid;   // 0..16383
        {
            int c = base >> 7, o = base & 127;
            ws[WT_VP + base] = vproj_w[o * 128 + c];
            ws[WT_OP + base] = oproj_w[o * 128 + c];
        }
        if (base < 8192) {
            int c = base >> 6, o = base & 63;
            ws[WT_SO1 + base] = so1_w[o * 128 + c];
            ws[WT_AW1 + base] = aw1_w[o * 128 + c];
        }
        if (base < 6144) {
            int c = base / 96, o = base - c * 96;
            ws[WT_SO2 + base] = so2_w[o * 64 + c];
        }
        if (base < 3072) {
            int c = base / 48, o = base - c * 48;
            ws[WT_AW2 + base] = aw2_w[o * 64 + c];
        }
        for (int t = base; t < 36864; t += 16384) {
            int c = t / 288; int rem = t - c * 288; int k = rem / 9, tap = rem - k * 9;
            ws[WT_C1 + t] = conf1_w[(k * 128 + c) * 9 + tap];
        }
    }
}

// ============================================================
// K1: per-window offsets + attn branches (+softmax, coords, entropy)
// ============================================================
__global__ __launch_bounds__(256) void win_kernel(
    const float* __restrict__ query,
    const float* __restrict__ so2_b,
    const float* __restrict__ gno_g, const float* __restrict__ gno_b,
    const float* __restrict__ aw2_b,
    const float* __restrict__ gna_g, const float* __restrict__ gna_b,
    float* __restrict__ ws, float* __restrict__ out)
{
    __shared__ float sA[8192];     // 32KB
    __shared__ float sYso[4096];   // y1 so-path [64][64]
    __shared__ float sYaw[4096];   // y1 aw-path [64][64]

    int tid = threadIdx.x;
    int bw  = blockIdx.x;
    int b   = bw >> 8;
    int win = bw & 255;
    int wy = win >> 4, wx = win & 15;
    int fb = bw & 3;          // tile semantics: index = bw % B
    int pix = tid & 63;
    int og  = ufl(tid >> 6);  // wave id 0..3 (uniform)

    // ---- load q window into sA[c*64+pix] ----
    const float* qbase = query + ((size_t)b << 21);
    for (int idx = tid; idx < 2048; idx += 256) {
        int c = idx >> 4, j = idx & 15;
        int row = j >> 1, half = j & 1;
        int gh = wy * 8 + row, gw0 = wx * 8 + half * 4;
        const float4 v = *(const float4*)(qbase + (c << 14) + (gh << 7) + gw0);
        *(float4*)(&sA[(c << 6) + (row << 3) + half * 4]) = v;
    }
    __syncthreads();

    // ---- so1 / aw1: 64x64 each, thread = (pix, 16 outputs) ----
    {
        float accs[16], acca[16];
#pragma unroll
        for (int k = 0; k < 16; ++k) { accs[k] = 0.f; acca[k] = 0.f; }
#pragma unroll 4
        for (int c = 0; c < 128; ++c) {
            float q = sA[(c << 6) + pix];
            const float* ws1 = ws + WT_SO1 + c * 64 + og * 16;
            const float* wa1 = ws + WT_AW1 + c * 64 + og * 16;
#pragma unroll
            for (int k = 0; k < 16; ++k) {
                accs[k] += ws1[k] * q;
                acca[k] += wa1[k] * q;
            }
        }
        const float* ba_s = ws + WS_SO1BA + fb * 64;
        const float* ba_a = ws + WS_AW1BA + fb * 64;
#pragma unroll
        for (int k = 0; k < 16; ++k) {
            int o = og * 16 + k;
            sYso[(o << 6) + pix] = accs[k] + ba_s[o];
            sYaw[(o << 6) + pix] = acca[k] + ba_a[o];
        }
    }
    __syncthreads();

    // ---- GroupNorm(so) ----
    {
        float s = 0.f, sq = 0.f;
        int base = tid * 16;
#pragma unroll
        for (int k = 0; k < 16; ++k) { float v = sYso[base + k]; s += v; sq += v * v; }
        sA[tid] = s; sA[256 + tid] = sq;
    }
    __syncthreads();
    if (tid < 8) {
        float s = 0.f, sq = 0.f;
        for (int k = 0; k < 32; ++k) { s += sA[tid * 32 + k]; sq += sA[256 + tid * 32 + k]; }
        float mu = s * (1.f / 512.f);
        float var = sq * (1.f / 512.f) - mu * mu;
        sA[512 + tid] = mu;
        sA[520 + tid] = 1.f / sqrtf(var + 1e-5f);
    }
    __syncthreads();
    {
        int base = tid * 16;
        int g = tid >> 5;
        int c = tid >> 2;
        float mu = sA[512 + g], rs = sA[520 + g];
        float ga = gno_g[c], be = gno_b[c];
#pragma unroll
        for (int k = 0; k < 16; ++k) {
            float v = (sYso[base + k] - mu) * rs * ga + be;
            sYso[base + k] = fmaxf(v, 0.f);
        }
    }
    __syncthreads();

    // ---- so2: 96x64 -> offsets into sA[1024 + ch*64 + pix] ----
    {
        float acc[24];
#pragma unroll
        for (int k = 0; k < 24; ++k) acc[k] = 0.f;
#pragma unroll 4
        for (int c = 0; c < 64; ++c) {
            float y = sYso[(c << 6) + pix];
            const float* w = ws + WT_SO2 + c * 96 + og * 24;
#pragma unroll
            for (int k = 0; k < 24; ++k) acc[k] += w[k] * y;
        }
#pragma unroll
        for (int k = 0; k < 24; ++k) {
            int ch = og * 24 + k;
            sA[1024 + (ch << 6) + pix] = acc[k] + so2_b[ch];
        }
    }
    __syncthreads();

    // ---- coords (reads offsets) + GroupNorm(aw) partials ----
    {
        int hh = og;
        int btrue = bw >> 8;
        float refx = (float)(pix & 7) * (1.f / 7.f);
        float refy = (float)(pix >> 3) * (1.f / 7.f);
        float* co = ws + WS_COORD + ((((size_t)bw * 64 + pix) * 4 + hh) * 24);
#pragma unroll
        for (int l = 0; l < 3; ++l) {
            float hs = ws[WS_HS + (btrue * 3 + l) * 4 + hh];
#pragma unroll
            for (int p = 0; p < 4; ++p) {
                int chx = ((hh * 3 + l) * 4 + p) * 2;
                float ox = sA[1024 + (chx << 6) + pix];
                float oy = sA[1024 + ((chx + 1) << 6) + pix];
                float x = fminf(fmaxf(refx + ox, 0.f), 1.f) * 2.f - 1.f;
                float y = fminf(fmaxf(refy + oy, 0.f), 1.f) * 2.f - 1.f;
                x = fminf(fmaxf(x * hs, -1.f), 1.f);
                y = fminf(fmaxf(y * hs, -1.f), 1.f);
                float ix = fminf(fmaxf(((x + 1.f) * 8.f - 1.f) * 0.5f, 0.f), 7.f);
                float iy = fminf(fmaxf(((y + 1.f) * 8.f - 1.f) * 0.5f, 0.f), 7.f);
                co[(l * 4 + p) * 2]     = ix;
                co[(l * 4 + p) * 2 + 1] = iy;
            }
        }
    }
    {
        float s = 0.f, sq = 0.f;
        int base = tid * 16;
#pragma unroll
        for (int k = 0; k < 16; ++k) { float v = sYaw[base + k]; s += v; sq += v * v; }
        sA[tid] = s; sA[256 + tid] = sq;
    }
    __syncthreads();
    if (tid < 8) {
        float s = 0.f, sq = 0.f;
        for (int k = 0; k < 32; ++k) { s += sA[tid * 32 + k]; sq += sA[256 + tid * 32 + k]; }
        float mu = s * (1.f / 512.f);
        float var = sq * (1.f / 512.f) - mu * mu;
        sA[512 + tid] = mu;
        sA[520 + tid] = 1.f / sqrtf(var + 1e-5f);
    }
    __syncthreads();
    {
        int base = tid * 16;
        int g = tid >> 5;
        int c = tid >> 2;
        float mu = sA[512 + g], rs = sA[520 + g];
        float ga = gna_g[c], be = gna_b[c];
#pragma unroll
        for (int k = 0; k < 16; ++k) {
            float v = (sYaw[base + k] - mu) * rs * ga + be;
            sYaw[base + k] = fmaxf(v, 0.f);
        }
    }
    __syncthreads();

    // ---- aw2: 48x64 -> attn_raw into sA[1024 + ch*64 + pix] ----
    {
        float acc[12];
#pragma unroll
        for (int k = 0; k < 12; ++k) acc[k] = 0.f;
#pragma unroll 4
        for (int c = 0; c < 64; ++c) {
            float y = sYaw[(c << 6) + pix];
            const float* w = ws + WT_AW2 + c * 48 + og * 12;
#pragma unroll
            for (int k = 0; k < 12; ++k) acc[k] += w[k] * y;
        }
        __syncthreads();
#pragma unroll
        for (int k = 0; k < 12; ++k) {
            int ch = og * 12 + k;
            sA[1024 + (ch << 6) + pix] = acc[k] + aw2_b[ch];
        }
    }
    __syncthreads();

    // ---- softmax over 12 per (pix, head) + entropy ----
    {
        int hh = og;
        const float* ad = ws + WS_ABSDT + fb * 3;
        float lg[12];
        float m = -1e30f;
#pragma unroll
        for (int q = 0; q < 12; ++q) {
            float v = sA[1024 + (((hh * 12 + q)) << 6) + pix] - ad[q >> 2];
            lg[q] = v; m = fmaxf(m, v);
        }
        float sum = 0.f;
#pragma unroll
        for (int q = 0; q < 12; ++q) { lg[q] = expf(lg[q] - m); sum += lg[q]; }
        float inv = 1.f / sum;
        float* at = ws + WS_ATTN + ((((size_t)bw * 64 + pix) * 4 + hh) * 12);
        float hent = 0.f;
#pragma unroll
        for (int q = 0; q < 12; ++q) {
            float p = lg[q] * inv;
            at[q] = p;
            float pp = p + 1e-8f;
            hent -= pp * logf(pp);
        }
        sA[pix * 4 + hh] = hent;
    }
    __syncthreads();
    if (tid < 64) {
        float e = 0.25f * (sA[tid * 4] + sA[tid * 4 + 1] + sA[tid * 4 + 2] + sA[tid * 4 + 3]);
        int gh = wy * 8 + (tid >> 3), gw = wx * 8 + (tid & 7);
        out[OUT_ENT + (b << 14) + (gh << 7) + gw] = e;
    }
}

// ============================================================
// K2: v_proj -> v_flat (N, BW, NH, pix, HD), HD contiguous
// ============================================================
__global__ __launch_bounds__(256) void vproj_kernel(
    const float* __restrict__ values, float* __restrict__ ws)
{
    __shared__ float sbuf[8448];   // staging [128][64]; then transpose [256 rows][33]
    int tid = threadIdx.x;
    int bid = blockIdx.x;
    int n = bid >> 10;
    int bw = bid & 1023;
    int b = bw >> 8; int win = bw & 255;
    int wy = win >> 4, wx = win & 15;
    const float* vbase = values + ((size_t)(b * 3 + n) << 21);
    for (int idx = tid; idx < 2048; idx += 256) {
        int c = idx >> 4, j = idx & 15;
        int row = j >> 1, half = j & 1;
        int gh = wy * 8 + row, gw0 = wx * 8 + half * 4;
        const float4 v = *(const float4*)(vbase + (c << 14) + (gh << 7) + gw0);
        *(float4*)(&sbuf[(c << 6) + (row << 3) + half * 4]) = v;
    }
    int pix = tid & 63;
    int og = ufl(tid >> 6);
    float vbr[32];
    {
        const float* vb = ws + WS_VB + n * 128 + og * 32;
#pragma unroll
        for (int k = 0; k < 32; ++k) vbr[k] = vb[k];
    }
    __syncthreads();
    float acc[32];
#pragma unroll
    for (int k = 0; k < 32; ++k) acc[k] = 0.f;
#pragma unroll 4
    for (int c = 0; c < 128; ++c) {
        float v = sbuf[(c << 6) + pix];
        const float* w = ws + WT_VP + c * 128 + og * 32;
#pragma unroll
        for (int k = 0; k < 32; ++k) acc[k] += w[k] * v;
    }
    __syncthreads();   // done reading staging
    int row = (og << 6) + pix;
#pragma unroll
    for (int k = 0; k < 32; ++k) sbuf[row * 33 + k] = acc[k] + vbr[k];
    __syncthreads();
    float* base2 = ws + WS_VFLAT + ((((size_t)n << 10) + bw) << 13);
#pragma unroll
    for (int i = 0; i < 8; ++i) {
        int f4 = (i * 256 + tid) * 4;
        int r = f4 >> 5, k = f4 & 31;
        float4 v = make_float4(sbuf[r * 33 + k], sbuf[r * 33 + k + 1],
                               sbuf[r * 33 + k + 2], sbuf[r * 33 + k + 3]);
        *(float4*)(base2 + f4) = v;
    }
}

// ============================================================
// K3: bilinear sample + head-weighted sum + oproj — LDS-resident
//     stage coords(24K)+attn(12K) once, v-slice(32K) per level;
//     acc[32 pix] in regs across levels; smem reused for oproj.
// ============================================================
__global__ __launch_bounds__(256) void sample_kernel(
    const float* __restrict__ oproj_b,
    float* __restrict__ ws, float* __restrict__ out)
{
    __shared__ float smem[17408];   // 68 KB: [0,6144) coords | [6144,9216) attn | [9216,17408) v-slice
    int tid = threadIdx.x;
    int bw = blockIdx.x;
    int b = bw >> 8; int win = bw & 255;
    int wy = win >> 4, wx = win & 15;
    int d  = tid & 31;
    int hh = (tid >> 5) & 3;
    int ph = tid >> 7;

    // stage coords + attn (contiguous per block)
    {
        const float* co = ws + WS_COORD + (size_t)bw * 6144;
        const float* at = ws + WS_ATTN + (size_t)bw * 3072;
        for (int i = tid; i < 1536; i += 256)
            *(float4*)(&smem[i * 4]) = *(const float4*)(co + i * 4);
        for (int i = tid; i < 768; i += 256)
            *(float4*)(&smem[6144 + i * 4]) = *(const float4*)(at + i * 4);
    }

    float acc[32];
#pragma unroll
    for (int q = 0; q < 32; ++q) acc[q] = 0.f;

    for (int l = 0; l < 3; ++l) {
        if (l) __syncthreads();          // previous level's reads done
        const float* vsrc = ws + WS_VFLAT + ((((size_t)l << 10) + bw) << 13);
        for (int i = tid; i < 2048; i += 256)
            *(float4*)(&smem[9216 + i * 4]) = *(const float4*)(vsrc + i * 4);
        __syncthreads();                  // v-slice (and, at l=0, coords/attn) visible

        const float* vb = &smem[9216 + hh * 2048 + d];
        for (int q = 0; q < 32; ++q) {
            int pix = ph * 32 + q;
            const float* c24 = &smem[(pix * 4 + hh) * 24 + l * 8];
            const float* a4  = &smem[6144 + (pix * 4 + hh) * 12 + l * 4];
            float a0 = 0.f;
#pragma unroll
            for (int p = 0; p < 4; ++p) {
                float ix = c24[p * 2];
                float iy = c24[p * 2 + 1];
                float a  = a4[p];
                float x0f = floorf(ix), y0f = floorf(iy);
                int x0 = (int)x0f, y0 = (int)y0f;
                float wxf = ix - x0f, wyf = iy - y0f;
                int x1 = x0 + 1; if (x1 > 7) x1 = 7;
                int y1 = y0 + 1; if (y1 > 7) y1 = 7;
                float v00 = vb[(((y0 << 3) + x0) << 5)];
                float v01 = vb[(((y0 << 3) + x1) << 5)];
                float v10 = vb[(((y1 << 3) + x0) << 5)];
                float v11 = vb[(((y1 << 3) + x1) << 5)];
                float top = v00 + (v01 - v00) * wxf;
                float bot = v10 + (v11 - v10) * wxf;
                a0 += a * (top + (bot - top) * wyf);
            }
            acc[q] += a0;
        }
    }
    __syncthreads();   // all reads of coords/attn/v done; reuse smem[0..8320) as ob

    // ob[c][pix], c = hh*32+d, stride 65
#pragma unroll
    for (int q = 0; q < 32; ++q)
        smem[(hh * 32 + d) * 65 + ph * 32 + q] = acc[q];
    __syncthreads();

    // oproj (transposed weights)
    int pix = tid & 63;
    int og = ufl(tid >> 6);
    float acc2[32];
#pragma unroll
    for (int k = 0; k < 32; ++k) acc2[k] = 0.f;
#pragma unroll 4
    for (int c = 0; c < 128; ++c) {
        float v = smem[c * 65 + pix];
        const float* w = ws + WT_OP + c * 128 + og * 32;
#pragma unroll
        for (int k = 0; k < 32; ++k) acc2[k] += w[k] * v;
    }
    int gh = wy * 8 + (pix >> 3), gw = wx * 8 + (pix & 7);
#pragma unroll
    for (int k = 0; k < 32; ++k) {
        int o = og * 32 + k;
        out[OUT_FUSED + ((size_t)(b * 128 + o) << 14) + (gh << 7) + gw] = acc2[k] + oproj_b[o];
    }
}

// ============================================================
// K4: conf head — 3x3 conv (128->32) + relu + 1x1 (32->1) + sigmoid
// ============================================================
__global__ __launch_bounds__(256) void conf_kernel(
    const float* __restrict__ fused, const float* __restrict__ conf1_b,
    const float* __restrict__ conf2_w, const float* __restrict__ conf2_b,
    const float* __restrict__ ws, float* __restrict__ out)
{
    __shared__ float tile[64 * 110];   // 64 ch x 10 rows x 11-col stride
    __shared__ float red[4][64];
    int tid = threadIdx.x;
    int bid = blockIdx.x;
    int b = bid >> 8;
    int t = bid & 255; int ty = t >> 4, tx = t & 15;
    int pix = tid & 63;
    int kg  = ufl(tid >> 6);
    int py = pix >> 3, px = pix & 7;
    int oy = ty * 8, ox = tx * 8;
    const float* fin = fused + ((size_t)b << 21);

    float acc[8];
#pragma unroll
    for (int j = 0; j < 8; ++j) acc[j] = 0.f;

    for (int cc = 0; cc < 2; ++cc) {
        __syncthreads();
        for (int idx = tid; idx < 6400; idx += 256) {
            int c = idx / 100;
            int rem = idx - c * 100;
            int r = rem / 10, col = rem - r * 10;
            int gy = oy + r - 1, gx = ox + col - 1;
            float v = 0.f;
            if (gy >= 0 && gy < 128 && gx >= 0 && gx < 128)
                v = fin[((size_t)(cc * 64 + c) << 14) + (gy << 7) + gx];
            tile[c * 110 + r * 11 + col] = v;
        }
        __syncthreads();
        for (int c = 0; c < 64; ++c) {
            float v[9];
#pragma unroll
            for (int dy = 0; dy < 3; ++dy)
#pragma unroll
                for (int dx = 0; dx < 3; ++dx)
                    v[dy * 3 + dx] = tile[c * 110 + (py + dy) * 11 + (px + dx)];
            const float* wp = ws + WT_C1 + ufl((cc * 64 + c) * 288 + kg * 72);
#pragma unroll
            for (int j = 0; j < 8; ++j) {
#pragma unroll
                for (int tap = 0; tap < 9; ++tap)
                    acc[j] += v[tap] * wp[j * 9 + tap];
            }
        }
    }
    float s = 0.f;
#pragma unroll
    for (int j = 0; j < 8; ++j) {
        int k = kg * 8 + j;
        s += fmaxf(acc[j] + conf1_b[k], 0.f) * conf2_w[k];
    }
    red[kg][pix] = s;
    __syncthreads();
    if (tid < 64) {
        float tot = red[0][tid] + red[1][tid] + red[2][tid] + red[3][tid] + conf2_b[0];
        float cf = 1.f / (1.f + expf(-tot));
        int gy = oy + (tid >> 3), gx = ox + (tid & 7);
        out[OUT_CONF + (b << 14) + (gy << 7) + gx] = cf;
    }
}

// ============================================================
extern "C" void kernel_launch(void* const* d_in, const int* in_sizes, int n_in,
                              void* d_out, int out_size, void* d_ws, size_t ws_size,
                              hipStream_t stream) {
    const float* query      = (const float*)d_in[0];
    const float* values     = (const float*)d_in[1];
    const float* rel_scalar = (const float*)d_in[2];
    const float* tgt_enc    = (const float*)d_in[3];
    const float* so1_w = (const float*)d_in[4];
    const float* so1_b = (const float*)d_in[5];
    const float* gno_g = (const float*)d_in[6];
    const float* gno_b = (const float*)d_in[7];
    const float* so2_w = (const float*)d_in[8];
    const float* so2_b = (const float*)d_in[9];
    const float* aw1_w = (const float*)d_in[10];
    const float* aw1_b = (const float*)d_in[11];
    const float* gna_g = (const float*)d_in[12];
    const float* gna_b = (const float*)d_in[13];
    const float* aw2_w = (const float*)d_in[14];
    const float* aw2_b = (const float*)d_in[15];
    const float* vproj_w = (const float*)d_in[16];
    const float* vproj_b = (const float*)d_in[17];
    const float* oproj_w = (const float*)d_in[18];
    const float* oproj_b = (const float*)d_in[19];
    const float* filmo_w = (const float*)d_in[20];
    const float* filmo_b = (const float*)d_in[21];
    const float* filma_w = (const float*)d_in[22];
    const float* filma_b = (const float*)d_in[23];
    const float* dts_w   = (const float*)d_in[24];
    const float* dts_b   = (const float*)d_in[25];
    const float* level_embed = (const float*)d_in[26];
    const float* conf1_w = (const float*)d_in[27];
    const float* conf1_b = (const float*)d_in[28];
    const float* conf2_w = (const float*)d_in[29];
    const float* conf2_b = (const float*)d_in[30];

    float* ws  = (float*)d_ws;
    float* out = (float*)d_out;

    prep_kernel<<<65, 256, 0, stream>>>(tgt_enc, filmo_w, filmo_b, filma_w, filma_b,
                                        so1_w, so1_b, aw1_w, aw1_b,
                                        so2_w, aw2_w,
                                        vproj_w, vproj_b, oproj_w, conf1_w,
                                        level_embed, rel_scalar, dts_w, dts_b, ws);
    win_kernel<<<BWTOT, 256, 0, stream>>>(query, so2_b, gno_g, gno_b,
                                          aw2_b, gna_g, gna_b, ws, out);
    vproj_kernel<<<NVAL * BWTOT, 256, 0, stream>>>(values, ws);
    sample_kernel<<<BWTOT, 256, 0, stream>>>(oproj_b, ws, out);
    conf_kernel<<<NB * 256, 256, 0, stream>>>(out, conf1_b, conf2_w, conf2_b, ws, out);
}

// Round 6
// 659.739 us; speedup vs baseline: 3.7010x; 1.0618x over previous
//
#include <hip/hip_runtime.h>
#include <math.h>

// ---- problem constants ----
#define NB 4
#define NVAL 3
#define NC 128
#define NHW 128
#define NHEAD 4
#define NPOINT 4
#define NLVL 3
#define WSZ 8
#define HD 32
#define NWIN 256      // 16x16 windows
#define BWTOT 1024    // NB * NWIN
#define NPIX 64       // WSZ*WSZ

// ---- workspace layout (float offsets) ----
#define WS_SO1BA 0                        // 4*64
#define WS_AW1BA 256                      // 4*64
#define WS_VB    512                      // 3*128
#define WS_HS    896                      // 4*3*4
#define WS_ABSDT 944                      // 4*3
// transposed weights (wT[c][o])
#define WT_VP    1024                     // 128*128
#define WT_OP    17408                    // 128*128
#define WT_SO1   33792                    // 128*64
#define WT_AW1   41984                    // 128*64
#define WT_SO2   50176                    // 64*96
#define WT_AW2   56320                    // 64*48
#define WT_C1    59392                    // 128*32*9
#define WS_COORD 96256                    // 1024*64*4*12*2
#define WS_ATTN  (96256 + 6291456)        // 1024*64*4*12
#define WS_VFLAT (96256 + 6291456 + 3145728)

// ---- output layout (float offsets) ----
#define OUT_FUSED 0
#define OUT_CONF  8388608                 // 4*128*128*128
#define OUT_ENT   (8388608 + 65536)

__device__ __forceinline__ int ufl(int x) { return __builtin_amdgcn_readfirstlane(x); }

// ============================================================
// K0: prep — film-folded biases, vproj level bias, hscale, |dt|,
//     + weight transposes (blocks 1..64)
// ============================================================
__global__ __launch_bounds__(256) void prep_kernel(
    const float* __restrict__ tgt_enc, const float* __restrict__ filmo_w, const float* __restrict__ filmo_b,
    const float* __restrict__ filma_w, const float* __restrict__ filma_b,
    const float* __restrict__ so1_w, const float* __restrict__ so1_b,
    const float* __restrict__ aw1_w, const float* __restrict__ aw1_b,
    const float* __restrict__ so2_w, const float* __restrict__ aw2_w,
    const float* __restrict__ vproj_w, const float* __restrict__ vproj_b,
    const float* __restrict__ oproj_w, const float* __restrict__ conf1_w,
    const float* __restrict__ level_embed,
    const float* __restrict__ rel_scalar, const float* __restrict__ dts_w, const float* __restrict__ dts_b,
    float* __restrict__ ws)
{
    int tid = threadIdx.x;
    if (blockIdx.x == 0) {
        __shared__ float film[1024];  // [which][b][c]
        for (int t = tid; t < 1024; t += 256) {
            int which = t >> 9; int b = (t >> 7) & 3; int c = t & 127;
            const float* fw = which ? filma_w : filmo_w;
            const float* fb = which ? filma_b : filmo_b;
            float acc = fb[c];
            for (int k = 0; k < 64; ++k) acc += tgt_enc[b * 64 + k] * fw[c * 64 + k];
            film[t] = acc;
        }
        __syncthreads();
        for (int t = tid; t < 512; t += 256) {
            int which = t >> 8; int fb = (t >> 6) & 3; int o = t & 63;
            const float* w  = which ? aw1_w : so1_w;
            const float* bb = which ? aw1_b : so1_b;
            const float* fm = &film[which * 512 + fb * 128];
            float acc = bb[o];
            for (int c = 0; c < 128; ++c) acc += w[o * 128 + c] * fm[c];
            ws[(which ? WS_AW1BA : WS_SO1BA) + fb * 64 + o] = acc;
        }
        for (int t = tid; t < 384; t += 256) {
            int n = t >> 7; int o = t & 127;
            float acc = vproj_b[o];
            for (int c = 0; c < 128; ++c) acc += level_embed[n * 128 + c] * vproj_w[o * 128 + c];
            ws[WS_VB + t] = acc;
        }
        if (tid < 48) {
            int b = tid / 12; int n = (tid / 4) % 3; int hh = tid & 3;
            float ad = fabsf(rel_scalar[b * 3 + n]);
            float s = 1.0f / (1.0f + expf(-(ad * dts_w[hh] + dts_b[hh])));
            ws[WS_HS + tid] = 1.0f + 0.5f * s;
        }
        if (tid < 12) ws[WS_ABSDT + tid] = fabsf(rel_scalar[tid]);
    } else {
        int base = (blockIdx.x - 1) * 256 + tid;   // 0..16383
        {
            int c = base >> 7, o = base & 127;
            ws[WT_VP + base] = vproj_w[o * 128 + c];
            ws[WT_OP + base] = oproj_w[o * 128 + c];
        }
        if (base < 8192) {
            int c = base >> 6, o = base & 63;
            ws[WT_SO1 + base] = so1_w[o * 128 + c];
            ws[WT_AW1 + base] = aw1_w[o * 128 + c];
        }
        if (base < 6144) {
            int c = base / 96, o = base - c * 96;
            ws[WT_SO2 + base] = so2_w[o * 64 + c];
        }
        if (base < 3072) {
            int c = base / 48, o = base - c * 48;
            ws[WT_AW2 + base] = aw2_w[o * 64 + c];
        }
        for (int t = base; t < 36864; t += 16384) {
            int c = t / 288; int rem = t - c * 288; int k = rem / 9, tap = rem - k * 9;
            ws[WT_C1 + t] = conf1_w[(k * 128 + c) * 9 + tap];
        }
    }
}

// ============================================================
// K1: per-window offsets + attn branches (+softmax, coords, entropy)
// ============================================================
__global__ __launch_bounds__(256) void win_kernel(
    const float* __restrict__ query,
    const float* __restrict__ so2_b,
    const float* __restrict__ gno_g, const float* __restrict__ gno_b,
    const float* __restrict__ aw2_b,
    const float* __restrict__ gna_g, const float* __restrict__ gna_b,
    float* __restrict__ ws, float* __restrict__ out)
{
    __shared__ float sA[8192];     // 32KB
    __shared__ float sYso[4096];   // y1 so-path [64][64]
    __shared__ float sYaw[4096];   // y1 aw-path [64][64]

    int tid = threadIdx.x;
    int bw  = blockIdx.x;
    int b   = bw >> 8;
    int win = bw & 255;
    int wy = win >> 4, wx = win & 15;
    int fb = bw & 3;          // tile semantics: index = bw % B
    int pix = tid & 63;
    int og  = ufl(tid >> 6);  // wave id 0..3 (uniform)

    // ---- load q window into sA[c*64+pix] ----
    const float* qbase = query + ((size_t)b << 21);
    for (int idx = tid; idx < 2048; idx += 256) {
        int c = idx >> 4, j = idx & 15;
        int row = j >> 1, half = j & 1;
        int gh = wy * 8 + row, gw0 = wx * 8 + half * 4;
        const float4 v = *(const float4*)(qbase + (c << 14) + (gh << 7) + gw0);
        *(float4*)(&sA[(c << 6) + (row << 3) + half * 4]) = v;
    }
    __syncthreads();

    // ---- so1 / aw1: 64x64 each, thread = (pix, 16 outputs) ----
    {
        float accs[16], acca[16];
#pragma unroll
        for (int k = 0; k < 16; ++k) { accs[k] = 0.f; acca[k] = 0.f; }
#pragma unroll 4
        for (int c = 0; c < 128; ++c) {
            float q = sA[(c << 6) + pix];
            const float* ws1 = ws + WT_SO1 + c * 64 + og * 16;
            const float* wa1 = ws + WT_AW1 + c * 64 + og * 16;
#pragma unroll
            for (int k = 0; k < 16; ++k) {
                accs[k] += ws1[k] * q;
                acca[k] += wa1[k] * q;
            }
        }
        const float* ba_s = ws + WS_SO1BA + fb * 64;
        const float* ba_a = ws + WS_AW1BA + fb * 64;
#pragma unroll
        for (int k = 0; k < 16; ++k) {
            int o = og * 16 + k;
            sYso[(o << 6) + pix] = accs[k] + ba_s[o];
            sYaw[(o << 6) + pix] = acca[k] + ba_a[o];
        }
    }
    __syncthreads();

    // ---- GroupNorm(so) ----
    {
        float s = 0.f, sq = 0.f;
        int base = tid * 16;
#pragma unroll
        for (int k = 0; k < 16; ++k) { float v = sYso[base + k]; s += v; sq += v * v; }
        sA[tid] = s; sA[256 + tid] = sq;
    }
    __syncthreads();
    if (tid < 8) {
        float s = 0.f, sq = 0.f;
        for (int k = 0; k < 32; ++k) { s += sA[tid * 32 + k]; sq += sA[256 + tid * 32 + k]; }
        float mu = s * (1.f / 512.f);
        float var = sq * (1.f / 512.f) - mu * mu;
        sA[512 + tid] = mu;
        sA[520 + tid] = 1.f / sqrtf(var + 1e-5f);
    }
    __syncthreads();
    {
        int base = tid * 16;
        int g = tid >> 5;
        int c = tid >> 2;
        float mu = sA[512 + g], rs = sA[520 + g];
        float ga = gno_g[c], be = gno_b[c];
#pragma unroll
        for (int k = 0; k < 16; ++k) {
            float v = (sYso[base + k] - mu) * rs * ga + be;
            sYso[base + k] = fmaxf(v, 0.f);
        }
    }
    __syncthreads();

    // ---- so2: 96x64 -> offsets into sA[1024 + ch*64 + pix] ----
    {
        float acc[24];
#pragma unroll
        for (int k = 0; k < 24; ++k) acc[k] = 0.f;
#pragma unroll 4
        for (int c = 0; c < 64; ++c) {
            float y = sYso[(c << 6) + pix];
            const float* w = ws + WT_SO2 + c * 96 + og * 24;
#pragma unroll
            for (int k = 0; k < 24; ++k) acc[k] += w[k] * y;
        }
#pragma unroll
        for (int k = 0; k < 24; ++k) {
            int ch = og * 24 + k;
            sA[1024 + (ch << 6) + pix] = acc[k] + so2_b[ch];
        }
    }
    __syncthreads();

    // ---- coords (reads offsets) + GroupNorm(aw) partials ----
    {
        int hh = og;
        int btrue = bw >> 8;
        float refx = (float)(pix & 7) * (1.f / 7.f);
        float refy = (float)(pix >> 3) * (1.f / 7.f);
        float* co = ws + WS_COORD + ((((size_t)bw * 64 + pix) * 4 + hh) * 24);
#pragma unroll
        for (int l = 0; l < 3; ++l) {
            float hs = ws[WS_HS + (btrue * 3 + l) * 4 + hh];
#pragma unroll
            for (int p = 0; p < 4; ++p) {
                int chx = ((hh * 3 + l) * 4 + p) * 2;
                float ox = sA[1024 + (chx << 6) + pix];
                float oy = sA[1024 + ((chx + 1) << 6) + pix];
                float x = fminf(fmaxf(refx + ox, 0.f), 1.f) * 2.f - 1.f;
                float y = fminf(fmaxf(refy + oy, 0.f), 1.f) * 2.f - 1.f;
                x = fminf(fmaxf(x * hs, -1.f), 1.f);
                y = fminf(fmaxf(y * hs, -1.f), 1.f);
                float ix = fminf(fmaxf(((x + 1.f) * 8.f - 1.f) * 0.5f, 0.f), 7.f);
                float iy = fminf(fmaxf(((y + 1.f) * 8.f - 1.f) * 0.5f, 0.f), 7.f);
                co[(l * 4 + p) * 2]     = ix;
                co[(l * 4 + p) * 2 + 1] = iy;
            }
        }
    }
    {
        float s = 0.f, sq = 0.f;
        int base = tid * 16;
#pragma unroll
        for (int k = 0; k < 16; ++k) { float v = sYaw[base + k]; s += v; sq += v * v; }
        sA[tid] = s; sA[256 + tid] = sq;
    }
    __syncthreads();
    if (tid < 8) {
        float s = 0.f, sq = 0.f;
        for (int k = 0; k < 32; ++k) { s += sA[tid * 32 + k]; sq += sA[256 + tid * 32 + k]; }
        float mu = s * (1.f / 512.f);
        float var = sq * (1.f / 512.f) - mu * mu;
        sA[512 + tid] = mu;
        sA[520 + tid] = 1.f / sqrtf(var + 1e-5f);
    }
    __syncthreads();
    {
        int base = tid * 16;
        int g = tid >> 5;
        int c = tid >> 2;
        float mu = sA[512 + g], rs = sA[520 + g];
        float ga = gna_g[c], be = gna_b[c];
#pragma unroll
        for (int k = 0; k < 16; ++k) {
            float v = (sYaw[base + k] - mu) * rs * ga + be;
            sYaw[base + k] = fmaxf(v, 0.f);
        }
    }
    __syncthreads();

    // ---- aw2: 48x64 -> attn_raw into sA[1024 + ch*64 + pix] ----
    {
        float acc[12];
#pragma unroll
        for (int k = 0; k < 12; ++k) acc[k] = 0.f;
#pragma unroll 4
        for (int c = 0; c < 64; ++c) {
            float y = sYaw[(c << 6) + pix];
            const float* w = ws + WT_AW2 + c * 48 + og * 12;
#pragma unroll
            for (int k = 0; k < 12; ++k) acc[k] += w[k] * y;
        }
        __syncthreads();
#pragma unroll
        for (int k = 0; k < 12; ++k) {
            int ch = og * 12 + k;
            sA[1024 + (ch << 6) + pix] = acc[k] + aw2_b[ch];
        }
    }
    __syncthreads();

    // ---- softmax over 12 per (pix, head) + entropy ----
    {
        int hh = og;
        const float* ad = ws + WS_ABSDT + fb * 3;
        float lg[12];
        float m = -1e30f;
#pragma unroll
        for (int q = 0; q < 12; ++q) {
            float v = sA[1024 + (((hh * 12 + q)) << 6) + pix] - ad[q >> 2];
            lg[q] = v; m = fmaxf(m, v);
        }
        float sum = 0.f;
#pragma unroll
        for (int q = 0; q < 12; ++q) { lg[q] = expf(lg[q] - m); sum += lg[q]; }
        float inv = 1.f / sum;
        float* at = ws + WS_ATTN + ((((size_t)bw * 64 + pix) * 4 + hh) * 12);
        float hent = 0.f;
#pragma unroll
        for (int q = 0; q < 12; ++q) {
            float p = lg[q] * inv;
            at[q] = p;
            float pp = p + 1e-8f;
            hent -= pp * logf(pp);
        }
        sA[pix * 4 + hh] = hent;
    }
    __syncthreads();
    if (tid < 64) {
        float e = 0.25f * (sA[tid * 4] + sA[tid * 4 + 1] + sA[tid * 4 + 2] + sA[tid * 4 + 3]);
        int gh = wy * 8 + (tid >> 3), gw = wx * 8 + (tid & 7);
        out[OUT_ENT + (b << 14) + (gh << 7) + gw] = e;
    }
}

// ============================================================
// K2: v_proj -> v_flat (N, BW, NH, pix, HD), HD contiguous
// ============================================================
__global__ __launch_bounds__(256) void vproj_kernel(
    const float* __restrict__ values, float* __restrict__ ws)
{
    __shared__ float sbuf[8448];   // staging [128][64]; then transpose [256 rows][33]
    int tid = threadIdx.x;
    int bid = blockIdx.x;
    int n = bid >> 10;
    int bw = bid & 1023;
    int b = bw >> 8; int win = bw & 255;
    int wy = win >> 4, wx = win & 15;
    const float* vbase = values + ((size_t)(b * 3 + n) << 21);
    for (int idx = tid; idx < 2048; idx += 256) {
        int c = idx >> 4, j = idx & 15;
        int row = j >> 1, half = j & 1;
        int gh = wy * 8 + row, gw0 = wx * 8 + half * 4;
        const float4 v = *(const float4*)(vbase + (c << 14) + (gh << 7) + gw0);
        *(float4*)(&sbuf[(c << 6) + (row << 3) + half * 4]) = v;
    }
    int pix = tid & 63;
    int og = ufl(tid >> 6);
    float vbr[32];
    {
        const float* vb = ws + WS_VB + n * 128 + og * 32;
#pragma unroll
        for (int k = 0; k < 32; ++k) vbr[k] = vb[k];
    }
    __syncthreads();
    float acc[32];
#pragma unroll
    for (int k = 0; k < 32; ++k) acc[k] = 0.f;
#pragma unroll 4
    for (int c = 0; c < 128; ++c) {
        float v = sbuf[(c << 6) + pix];
        const float* w = ws + WT_VP + c * 128 + og * 32;
#pragma unroll
        for (int k = 0; k < 32; ++k) acc[k] += w[k] * v;
    }
    __syncthreads();   // done reading staging
    int row = (og << 6) + pix;
#pragma unroll
    for (int k = 0; k < 32; ++k) sbuf[row * 33 + k] = acc[k] + vbr[k];
    __syncthreads();
    float* base2 = ws + WS_VFLAT + ((((size_t)n << 10) + bw) << 13);
#pragma unroll
    for (int i = 0; i < 8; ++i) {
        int f4 = (i * 256 + tid) * 4;
        int r = f4 >> 5, k = f4 & 31;
        float4 v = make_float4(sbuf[r * 33 + k], sbuf[r * 33 + k + 1],
                               sbuf[r * 33 + k + 2], sbuf[r * 33 + k + 3]);
        *(float4*)(base2 + f4) = v;
    }
}

// ============================================================
// K3: bilinear sample + head-weighted sum + oproj
//     thread = (pix, head-wave); acc[32] static; V in LDS stride-36
//     (36 == 4 mod 32 -> balanced bank quads, b128 conflict-free);
//     coords/attn read as float4 straight from global (L2-hot).
// ============================================================
__global__ __launch_bounds__(256, 4) void sample_kernel(
    const float* __restrict__ oproj_b,
    float* __restrict__ ws, float* __restrict__ out)
{
    __shared__ float smem[9216];   // v-slice [256 rows][36]; reused as ob[128][65]
    int tid = threadIdx.x;
    int bw = blockIdx.x;
    int b = bw >> 8; int win = bw & 255;
    int wy = win >> 4, wx = win & 15;
    int pix = tid & 63;
    int hh = ufl(tid >> 6);        // wave-uniform head

    const float* co = ws + WS_COORD + ((size_t)(bw * 64 + pix) * 4 + hh) * 24;
    const float* at = ws + WS_ATTN  + ((size_t)(bw * 64 + pix) * 4 + hh) * 12;

    float acc[32];
#pragma unroll
    for (int k = 0; k < 32; ++k) acc[k] = 0.f;

    for (int l = 0; l < 3; ++l) {
        // per-level coords+attn straight from global (read once each)
        float4 cxy0 = *(const float4*)(co + l * 8);
        float4 cxy1 = *(const float4*)(co + l * 8 + 4);
        float4 a4   = *(const float4*)(at + l * 4);
        if (l) __syncthreads();              // prev level reads done
        const float* vsrc = ws + WS_VFLAT + ((((size_t)l << 10) + bw) << 13);
        for (int i = tid; i < 2048; i += 256) {
            float4 v = *(const float4*)(vsrc + i * 4);
            int r = i >> 3, c4 = (i & 7) << 2;
            *(float4*)(&smem[r * 36 + c4]) = v;
        }
        __syncthreads();

        const float* vb = &smem[hh * (64 * 36)];
        float ixs[4] = {cxy0.x, cxy0.z, cxy1.x, cxy1.z};
        float iys[4] = {cxy0.y, cxy0.w, cxy1.y, cxy1.w};
        float as4[4] = {a4.x, a4.y, a4.z, a4.w};
#pragma unroll
        for (int p = 0; p < 4; ++p) {
            float ix = ixs[p], iy = iys[p], a = as4[p];
            float x0f = floorf(ix), y0f = floorf(iy);
            int x0 = (int)x0f, y0 = (int)y0f;
            float wxf = ix - x0f, wyf = iy - y0f;
            int x1 = x0 + 1; if (x1 > 7) x1 = 7;
            int y1 = y0 + 1; if (y1 > 7) y1 = 7;
            float w00 = a * (1.f - wxf) * (1.f - wyf);
            float w01 = a * wxf * (1.f - wyf);
            float w10 = a * (1.f - wxf) * wyf;
            float w11 = a * wxf * wyf;
            const float* r00 = vb + ((y0 << 3) + x0) * 36;
            const float* r01 = vb + ((y0 << 3) + x1) * 36;
            const float* r10 = vb + ((y1 << 3) + x0) * 36;
            const float* r11 = vb + ((y1 << 3) + x1) * 36;
#pragma unroll
            for (int ch = 0; ch < 8; ++ch) {
                float4 v00 = *(const float4*)(r00 + (ch << 2));
                float4 v01 = *(const float4*)(r01 + (ch << 2));
                float4 v10 = *(const float4*)(r10 + (ch << 2));
                float4 v11 = *(const float4*)(r11 + (ch << 2));
                acc[(ch << 2) + 0] += w00 * v00.x + w01 * v01.x + w10 * v10.x + w11 * v11.x;
                acc[(ch << 2) + 1] += w00 * v00.y + w01 * v01.y + w10 * v10.y + w11 * v11.y;
                acc[(ch << 2) + 2] += w00 * v00.z + w01 * v01.z + w10 * v10.z + w11 * v11.z;
                acc[(ch << 2) + 3] += w00 * v00.w + w01 * v01.w + w10 * v10.w + w11 * v11.w;
            }
        }
    }
    __syncthreads();   // done with v; reuse smem as ob[c][pix] stride 65
#pragma unroll
    for (int k = 0; k < 32; ++k)
        smem[(hh * 32 + k) * 65 + pix] = acc[k];
    __syncthreads();

    // oproj (transposed weights, uniform -> scalar loads)
    float acc2[32];
#pragma unroll
    for (int k = 0; k < 32; ++k) acc2[k] = 0.f;
#pragma unroll 4
    for (int c = 0; c < 128; ++c) {
        float v = smem[c * 65 + pix];
        const float* w = ws + WT_OP + c * 128 + hh * 32;
#pragma unroll
        for (int k = 0; k < 32; ++k) acc2[k] += w[k] * v;
    }
    int gh = wy * 8 + (pix >> 3), gw = wx * 8 + (pix & 7);
#pragma unroll
    for (int k = 0; k < 32; ++k) {
        int o = hh * 32 + k;
        out[OUT_FUSED + ((size_t)(b * 128 + o) << 14) + (gh << 7) + gw] = acc2[k] + oproj_b[o];
    }
}

// ============================================================
// K4: conf head — 3x3 conv (128->32) + relu + 1x1 (32->1) + sigmoid
// ============================================================
__global__ __launch_bounds__(256) void conf_kernel(
    const float* __restrict__ fused, const float* __restrict__ conf1_b,
    const float* __restrict__ conf2_w, const float* __restrict__ conf2_b,
    const float* __restrict__ ws, float* __restrict__ out)
{
    __shared__ float tile[64 * 110];   // 64 ch x 10 rows x 11-col stride
    __shared__ float red[4][64];
    int tid = threadIdx.x;
    int bid = blockIdx.x;
    int b = bid >> 8;
    int t = bid & 255; int ty = t >> 4, tx = t & 15;
    int pix = tid & 63;
    int kg  = ufl(tid >> 6);
    int py = pix >> 3, px = pix & 7;
    int oy = ty * 8, ox = tx * 8;
    const float* fin = fused + ((size_t)b << 21);

    float acc[8];
#pragma unroll
    for (int j = 0; j < 8; ++j) acc[j] = 0.f;

    for (int cc = 0; cc < 2; ++cc) {
        __syncthreads();
        for (int idx = tid; idx < 6400; idx += 256) {
            int c = idx / 100;
            int rem = idx - c * 100;
            int r = rem / 10, col = rem - r * 10;
            int gy = oy + r - 1, gx = ox + col - 1;
            float v = 0.f;
            if (gy >= 0 && gy < 128 && gx >= 0 && gx < 128)
                v = fin[((size_t)(cc * 64 + c) << 14) + (gy << 7) + gx];
            tile[c * 110 + r * 11 + col] = v;
        }
        __syncthreads();
        for (int c = 0; c < 64; ++c) {
            float v[9];
#pragma unroll
            for (int dy = 0; dy < 3; ++dy)
#pragma unroll
                for (int dx = 0; dx < 3; ++dx)
                    v[dy * 3 + dx] = tile[c * 110 + (py + dy) * 11 + (px + dx)];
            const float* wp = ws + WT_C1 + ufl((cc * 64 + c) * 288 + kg * 72);
#pragma unroll
            for (int j = 0; j < 8; ++j) {
#pragma unroll
                for (int tap = 0; tap < 9; ++tap)
                    acc[j] += v[tap] * wp[j * 9 + tap];
            }
        }
    }
    float s = 0.f;
#pragma unroll
    for (int j = 0; j < 8; ++j) {
        int k = kg * 8 + j;
        s += fmaxf(acc[j] + conf1_b[k], 0.f) * conf2_w[k];
    }
    red[kg][pix] = s;
    __syncthreads();
    if (tid < 64) {
        float tot = red[0][tid] + red[1][tid] + red[2][tid] + red[3][tid] + conf2_b[0];
        float cf = 1.f / (1.f + expf(-tot));
        int gy = oy + (tid >> 3), gx = ox + (tid & 7);
        out[OUT_CONF + (b << 14) + (gy << 7) + gx] = cf;
    }
}

// ============================================================
extern "C" void kernel_launch(void* const* d_in, const int* in_sizes, int n_in,
                              void* d_out, int out_size, void* d_ws, size_t ws_size,
                              hipStream_t stream) {
    const float* query      = (const float*)d_in[0];
    const float* values     = (const float*)d_in[1];
    const float* rel_scalar = (const float*)d_in[2];
    const float* tgt_enc    = (const float*)d_in[3];
    const float* so1_w = (const float*)d_in[4];
    const float* so1_b = (const float*)d_in[5];
    const float* gno_g = (const float*)d_in[6];
    const float* gno_b = (const float*)d_in[7];
    const float* so2_w = (const float*)d_in[8];
    const float* so2_b = (const float*)d_in[9];
    const float* aw1_w = (const float*)d_in[10];
    const float* aw1_b = (const float*)d_in[11];
    const float* gna_g = (const float*)d_in[12];
    const float* gna_b = (const float*)d_in[13];
    const float* aw2_w = (const float*)d_in[14];
    const float* aw2_b = (const float*)d_in[15];
    const float* vproj_w = (const float*)d_in[16];
    const float* vproj_b = (const float*)d_in[17];
    const float* oproj_w = (const float*)d_in[18];
    const float* oproj_b = (const float*)d_in[19];
    const float* filmo_w = (const float*)d_in[20];
    const float* filmo_b = (const float*)d_in[21];
    const float* filma_w = (const float*)d_in[22];
    const float* filma_b = (const float*)d_in[23];
    const float* dts_w   = (const float*)d_in[24];
    const float* dts_b   = (const float*)d_in[25];
    const float* level_embed = (const float*)d_in[26];
    const float* conf1_w = (const float*)d_in[27];
    const float* conf1_b = (const float*)d_in[28];
    const float* conf2_w = (const float*)d_in[29];
    const float* conf2_b = (const float*)d_in[30];

    float* ws  = (float*)d_ws;
    float* out = (float*)d_out;

    prep_kernel<<<65, 256, 0, stream>>>(tgt_enc, filmo_w, filmo_b, filma_w, filma_b,
                                        so1_w, so1_b, aw1_w, aw1_b,
                                        so2_w, aw2_w,
                                        vproj_w, vproj_b, oproj_w, conf1_w,
                                        level_embed, rel_scalar, dts_w, dts_b, ws);
    win_kernel<<<BWTOT, 256, 0, stream>>>(query, so2_b, gno_g, gno_b,
                                          aw2_b, gna_g, gna_b, ws, out);
    vproj_kernel<<<NVAL * BWTOT, 256, 0, stream>>>(values, ws);
    sample_kernel<<<BWTOT, 256, 0, stream>>>(oproj_b, ws, out);
    conf_kernel<<<NB * 256, 256, 0, stream>>>(out, conf1_b, conf2_w, conf2_b, ws, out);
}